// Round 6
// baseline (288.998 us; speedup 1.0000x reference)
//
#include <hip/hip_runtime.h>
#include <cstddef>
#include <cstdint>

#define NEG_SLOPE 0.2f

__device__ __forceinline__ unsigned short f2bf(float f) {
    unsigned int u = __float_as_uint(f);
    u = (u + 0x7fff + ((u >> 16) & 1)) >> 16;   // round-to-nearest-even
    return (unsigned short)u;
}
__device__ __forceinline__ float bf_lo(unsigned int u) { return __uint_as_float(u << 16); }
__device__ __forceinline__ float bf_hi(unsigned int u) { return __uint_as_float(u & 0xffff0000u); }

typedef __attribute__((ext_vector_type(8))) short bf16x8;   // MFMA A/B frag (4 VGPRs)
typedef __attribute__((ext_vector_type(4))) float f32x4;    // MFMA C/D frag
typedef __attribute__((ext_vector_type(2))) float f32x2;    // v_pk_fma_f32 pair

// ---------------- binned CSR build ----------------
// Bucket = dst >> 7 (128 nodes/bucket). Edges packed (src<<7)|dstLow (src<2^17).

constexpr int BIN_BLOCKS = 256;
constexpr int MAX_NBK = 1024;            // supports N <= 131072 (= packing limit)

__global__ __launch_bounds__(256) void zero_k(int* __restrict__ p, int n) {
    int i = blockIdx.x * blockDim.x + threadIdx.x;
    if (i < n) p[i] = 0;
}

__global__ __launch_bounds__(256) void bin_hist_k(const int* __restrict__ dst, int E,
                                                  int* __restrict__ btot,
                                                  int* __restrict__ blkoff,
                                                  int nbk, int chunk) {
    __shared__ int hist[MAX_NBK];
    for (int i = threadIdx.x; i < nbk; i += 256) hist[i] = 0;
    __syncthreads();
    const int lo = blockIdx.x * chunk;
    const int hi = min(lo + chunk, E);
    for (int e = lo + threadIdx.x; e < hi; e += 256)
        atomicAdd(&hist[dst[e] >> 7], 1);
    __syncthreads();
    const int B = gridDim.x;
    for (int i = threadIdx.x; i < nbk; i += 256)
        blkoff[i * B + blockIdx.x] = atomicAdd(&btot[i], hist[i]);
}

// exclusive scan of nbk (<=1024) bucket totals -> obk[nbk+1]  (wave-parallel)
__global__ __launch_bounds__(256) void scan_small_k(const int* __restrict__ btot,
                                                    int* __restrict__ obk, int nbk) {
    __shared__ int sh[MAX_NBK];
    const int tid = threadIdx.x;
    for (int i = tid; i < nbk; i += 256) sh[i] = btot[i];
    __syncthreads();
    if (tid < 64) {
        int run = 0;
        for (int b0 = 0; b0 < nbk; b0 += 64) {
            const int i = b0 + tid;
            int v = (i < nbk) ? sh[i] : 0;
            int inc = v;
#pragma unroll
            for (int o = 1; o < 64; o <<= 1) {
                int u = __shfl_up(inc, o);
                if (tid >= o) inc += u;
            }
            if (i < nbk) sh[i] = run + inc - v;       // exclusive
            run += __shfl(inc, 63);
        }
        if (tid == 0) obk[nbk] = run;                 // total edge count
    }
    __syncthreads();
    for (int i = tid; i < nbk; i += 256) obk[i] = sh[i];
}

__global__ __launch_bounds__(256) void bin_scatter_k(const int* __restrict__ ei, int E,
                                                     const int* __restrict__ obk,
                                                     const int* __restrict__ blkoff,
                                                     int* __restrict__ eb, int nbk,
                                                     int chunk) {
    __shared__ int cur[MAX_NBK];
    __shared__ int off_s[MAX_NBK];
    const int B = gridDim.x;
    for (int i = threadIdx.x; i < nbk; i += 256) {
        cur[i] = 0;
        off_s[i] = obk[i] + blkoff[i * B + blockIdx.x];
    }
    __syncthreads();
    const int lo = blockIdx.x * chunk;
    const int hi = min(lo + chunk, E);
    for (int e = lo + threadIdx.x; e < hi; e += 256) {
        int s = ei[e];
        int d = ei[E + e];
        int b = d >> 7;
        int idx = atomicAdd(&cur[b], 1);
        eb[off_s[b] + idx] = (s << 7) | (d & 127);
    }
}

__global__ __launch_bounds__(256) void bucket_build_k(const int* __restrict__ eb,
                                                      const int* __restrict__ obk,
                                                      int* __restrict__ row_ptr,
                                                      int* __restrict__ col,
                                                      int n, int nbk) {
    __shared__ int c[128];
    __shared__ int rp[128];
    const int b = blockIdx.x;
    const int t = threadIdx.x;
    const int beg = obk[b];
    const int end = obk[b + 1];
    const int bbase = beg + b * 128;     // preceding buckets are full (128 loops each)
    if (t < 128) c[t] = 1;               // self-loop pre-count
    __syncthreads();
    for (int i = beg + t; i < end; i += 256)
        atomicAdd(&c[eb[i] & 127], 1);
    __syncthreads();
    if (t < 64) {                        // exclusive scan of 128 degrees (wave 0)
        int v0 = c[2 * t], v1 = c[2 * t + 1];
        int pair = v0 + v1;
        int inc = pair;
        for (int o = 1; o < 64; o <<= 1) {
            int u = __shfl_up(inc, o);
            if (t >= o) inc += u;
        }
        int ex = inc - pair;
        rp[2 * t] = bbase + ex;
        rp[2 * t + 1] = bbase + ex + v0;
    }
    __syncthreads();
    const int node = b * 128 + t;
    if (t < 128 && node < n) {
        row_ptr[node] = rp[t];
        col[rp[t]] = node;               // self-loop in slot 0
    }
    if (b == 0 && t == 0) row_ptr[n] = obk[nbk] + n;
    __syncthreads();
    if (t < 128) c[t] = 1;
    __syncthreads();
    for (int i = beg + t; i < end; i += 256) {
        int p = eb[i];
        int dl = p & 127;
        int idx = atomicAdd(&c[dl], 1);
        col[rp[dl] + idx] = p >> 7;
    }
}

// ---------------- degree-sorted tile permutation -----------------------------
// One wave per 64-node tile: bitonic-sort lanes by degree so subgroups sharing
// a wave in the agg kernels get similar-degree nodes (kills max-of-8 pass
// divergence). perm[slot] = node id; bijective within each tile.

__global__ __launch_bounds__(256) void tile_sort_k(const int* __restrict__ row_ptr,
                                                   int* __restrict__ perm,
                                                   int n, int ntiles) {
    const int wv = threadIdx.x >> 6;
    const int lane = threadIdx.x & 63;
    const int tile = blockIdx.x * 4 + wv;
    if (tile >= ntiles) return;
    const int node = tile * 64 + lane;
    const int deg = (node < n) ? (row_ptr[node + 1] - row_ptr[node]) : 0x3fffff;
    int key = (deg << 6) | lane;         // composite key, all distinct
    // bitonic sort ascending across the 64 lanes
    for (int k = 2; k <= 64; k <<= 1) {
        for (int j = k >> 1; j > 0; j >>= 1) {
            const int pkey = __shfl_xor(key, j);
            const bool up = ((lane & k) == 0);
            const bool keep_min = (((lane & j) == 0) == up);
            key = keep_min ? min(key, pkey) : max(key, pkey);
        }
    }
    perm[tile * 64 + lane] = tile * 64 + (key & 63);
}

// ---------------- layer 1 dense: fp32 x -> MFMA bf16 GEMM + attention dots ----

template <int K, int F>
__launch_bounds__(256)
__global__ void gemm_mfma_k(const float* __restrict__ x, const float* __restrict__ W,
                            const float* __restrict__ a_s, const float* __restrict__ a_d,
                            unsigned short* __restrict__ hb, float2* __restrict__ ssd,
                            int n) {
    constexpr int MT = 64;               // rows per block
    constexpr int KP = K + 8;            // padded inner stride (bf16 elems)
    constexpr int NT = F / 16;           // n-tiles per wave
    constexpr int KC = K / 32;           // k-steps

    __shared__ unsigned short xb[MT * KP];
    __shared__ unsigned short wb[F * KP];

    const int tid = threadIdx.x;
    const int lane = tid & 63;
    const int wv = tid >> 6;             // wave id 0..3
    const int base = blockIdx.x * MT;

    for (int i = tid; i < MT * K / 4; i += 256) {
        int row = i / (K / 4);
        int c4 = i % (K / 4);
        float4 v = make_float4(0.f, 0.f, 0.f, 0.f);
        if (base + row < n)
            v = *(const float4*)&x[(size_t)(base + row) * K + 4 * c4];
        ushort4 b;
        b.x = f2bf(v.x); b.y = f2bf(v.y); b.z = f2bf(v.z); b.w = f2bf(v.w);
        *(ushort4*)&xb[row * KP + 4 * c4] = b;
    }
    // W staging, k-contiguous ushort4 stores (lane stride 2*KP B -> ~8 banks)
    for (int i = tid; i < K * F / 4; i += 256) {
        int nn = i % F;
        int k4 = i / F;
        ushort4 b;
        b.x = f2bf(W[(size_t)(4 * k4 + 0) * F + nn]);
        b.y = f2bf(W[(size_t)(4 * k4 + 1) * F + nn]);
        b.z = f2bf(W[(size_t)(4 * k4 + 2) * F + nn]);
        b.w = f2bf(W[(size_t)(4 * k4 + 3) * F + nn]);
        *(ushort4*)&wb[nn * KP + 4 * k4] = b;
    }
    __syncthreads();

    const int mrow = lane & 15;
    const int quad = lane >> 4;

    f32x4 acc[NT];
#pragma unroll
    for (int t = 0; t < NT; ++t) acc[t] = (f32x4){0.f, 0.f, 0.f, 0.f};

#pragma unroll
    for (int kc = 0; kc < KC; ++kc) {
        const int kof = kc * 32 + quad * 8;
        bf16x8 af = *(const bf16x8*)&xb[(wv * 16 + mrow) * KP + kof];
#pragma unroll
        for (int t = 0; t < NT; ++t) {
            bf16x8 bfr = *(const bf16x8*)&wb[(t * 16 + mrow) * KP + kof];
            acc[t] = __builtin_amdgcn_mfma_f32_16x16x32_bf16(af, bfr, acc[t], 0, 0, 0);
        }
    }

    float as_c[NT], ad_c[NT];
#pragma unroll
    for (int t = 0; t < NT; ++t) { as_c[t] = a_s[t * 16 + mrow]; ad_c[t] = a_d[t * 16 + mrow]; }

#pragma unroll
    for (int r = 0; r < 4; ++r) {
        const int node = base + wv * 16 + quad * 4 + r;
        float ps = 0.f, pd = 0.f;
#pragma unroll
        for (int t = 0; t < NT; ++t) {
            ps = fmaf(acc[t][r], as_c[t], ps);
            pd = fmaf(acc[t][r], ad_c[t], pd);
        }
#pragma unroll
        for (int o = 1; o < 16; o <<= 1) {
            ps += __shfl_xor(ps, o);
            pd += __shfl_xor(pd, o);
        }
        if (node < n) {
#pragma unroll
            for (int t = 0; t < NT; ++t)
                hb[(size_t)node * F + t * 16 + mrow] = f2bf(acc[t][r]);
            if (mrow == 0) ssd[node] = make_float2(ps, pd);
        }
    }
}

// ---------------- fused agg(layer i) + gemm(layer i+1) -----------------------
// 512 threads: 8 waves x 8 nodes (S=8 lanes/node) aggregate the 64-row tile
// straight into LDS, then waves 0..3 run the MFMA. Degree-sorted perm gives
// each wave similar-degree nodes. Hot loop is branchless + phase-split.

template <int K, int F>
__launch_bounds__(512)
__global__ void agg_gemm_k(const int* __restrict__ row_ptr, const int* __restrict__ col,
                           const int* __restrict__ perm,
                           const unsigned short* __restrict__ hbi,
                           const float2* __restrict__ ssdi,
                           const float* __restrict__ bias,
                           const float* __restrict__ W,
                           const float* __restrict__ a_s, const float* __restrict__ a_d,
                           unsigned short* __restrict__ hbo, float2* __restrict__ ssdo,
                           int n) {
    static_assert(K == 64, "agg phase assumes 64 input channels");
    constexpr int S = 8;                 // lanes per node (= K/8)
    constexpr int MT = 64;               // nodes (= GEMM rows) per block
    constexpr int KP = K + 8;
    constexpr int NT = F / 16;
    constexpr int KC = K / 32;

    __shared__ unsigned short xb[MT * KP];
    __shared__ unsigned short wb[F * KP];

    const int tid = threadIdx.x;
    const int lane = tid & 63;
    const int wv = tid >> 6;             // 0..7
    const int base = blockIdx.x * MT;

    // stage W (read before phase 1; consumed after the single barrier)
    for (int i = tid; i < K * F / 4; i += 512) {
        int nn = i % F;
        int k4 = i / F;
        ushort4 b;
        b.x = f2bf(W[(size_t)(4 * k4 + 0) * F + nn]);
        b.y = f2bf(W[(size_t)(4 * k4 + 1) * F + nn]);
        b.z = f2bf(W[(size_t)(4 * k4 + 2) * F + nn]);
        b.w = f2bf(W[(size_t)(4 * k4 + 3) * F + nn]);
        *(ushort4*)&wb[nn * KP + 4 * k4] = b;
    }

    // ---- phase 1: softmax aggregation, 8 lanes per node (degree-sorted) ----
    const int ls = lane & (S - 1);       // channel octet index (NL == S, Q == 1)
    const int lbase = lane - ls;
    const int nl = tid >> 3;             // sorted slot 0..63
    const int pnode = perm[base + nl];   // node this subgroup aggregates
    const int slot = pnode - base;       // its row in the A-tile (bijective)

    float val[8] = {0.f, 0.f, 0.f, 0.f, 0.f, 0.f, 0.f, 0.f};
    if (pnode < n) {
        const int beg = row_ptr[pnode];
        const int end = row_ptr[pnode + 1];
        const float2 sn = ssdi[pnode];
        const float sdv = sn.y;
        float z0 = sn.x + sdv;
        z0 = (z0 > 0.f) ? z0 : NEG_SLOPE * z0;   // self-loop logit = softmax shift

        float s = 0.f;
        f32x2 acc2[4];
#pragma unroll
        for (int i = 0; i < 4; ++i) acc2[i] = (f32x2){0.f, 0.f};

        // prologue: pass-0 logit
        const int j0 = beg + ls;
        const bool vld0 = j0 < end;
        int c_cur = vld0 ? col[j0] : 0;
        float w_cur = 0.f;
        if (vld0) {
            float z = ssdi[c_cur].x + sdv;
            z = (z > 0.f) ? z : NEG_SLOPE * z;
            w_cur = __expf(z - z0);
        }

        for (int b0 = beg; b0 < end; b0 += S) {
            const int jn = b0 + S + ls;
            const bool vn = jn < end;
            const int c_next = vn ? col[jn] : 0;     // issued before gathers

            s += w_cur;
            const unsigned int pk =
                ((unsigned int)f2bf(w_cur) << 17) | (unsigned int)c_cur;

            // phase A: all cross-lane moves (pk of 8 edges of this node)
            unsigned int pe[8];
#pragma unroll
            for (int t = 0; t < 8; ++t)
                pe[t] = (unsigned int)__shfl((int)pk, lbase + t);

            // phase B: all 8 gathers issued back-to-back, none consumed yet
            uint4 hv[8];
#pragma unroll
            for (int t = 0; t < 8; ++t)
                hv[t] = *(const uint4*)&hbi[(size_t)(pe[t] & 0x1ffffu) * K + 8 * ls];

            __builtin_amdgcn_sched_barrier(0);   // keep consume out of the load pack

            // next-pass logit chain overlaps the 8 in-flight gathers
            float w_next = 0.f;
            if (vn) {
                float z = ssdi[c_next].x + sdv;
                z = (z > 0.f) ? z : NEG_SLOPE * z;
                w_next = __expf(z - z0);
            }

            // phase C: consume (wt == 0 for tail slots -> zero contribution)
#pragma unroll
            for (int t = 0; t < 8; ++t) {
                const float wt = __uint_as_float((pe[t] >> 17) << 16);
                f32x2 p;
                p.x = bf_lo(hv[t].x); p.y = bf_hi(hv[t].x); acc2[0] += p * wt;
                p.x = bf_lo(hv[t].y); p.y = bf_hi(hv[t].y); acc2[1] += p * wt;
                p.x = bf_lo(hv[t].z); p.y = bf_hi(hv[t].z); acc2[2] += p * wt;
                p.x = bf_lo(hv[t].w); p.y = bf_hi(hv[t].w); acc2[3] += p * wt;
            }
            c_cur = c_next;
            w_cur = w_next;
        }
#pragma unroll
        for (int o = S / 2; o; o >>= 1) s += __shfl_xor(s, o);
        const float inv = 1.f / (s + 1e-16f);
        val[0] = acc2[0].x; val[1] = acc2[0].y; val[2] = acc2[1].x; val[3] = acc2[1].y;
        val[4] = acc2[2].x; val[5] = acc2[2].y; val[6] = acc2[3].x; val[7] = acc2[3].y;
#pragma unroll
        for (int i = 0; i < 8; ++i)
            val[i] = fmaxf(val[i] * inv + bias[8 * ls + i], 0.f);   // bias + relu
    }
    {   // bf16 row into the A-tile slot of THIS node (zeros for pnode >= n)
        ushort4 p0, p1;
        p0.x = f2bf(val[0]); p0.y = f2bf(val[1]); p0.z = f2bf(val[2]); p0.w = f2bf(val[3]);
        p1.x = f2bf(val[4]); p1.y = f2bf(val[5]); p1.z = f2bf(val[6]); p1.w = f2bf(val[7]);
        *(ushort4*)&xb[slot * KP + 8 * ls] = p0;
        *(ushort4*)&xb[slot * KP + 8 * ls + 4] = p1;
    }

    __syncthreads();

    // ---- phase 2: h = o @ W + fused attention dots (waves 0..3) ----
    if (wv < 4) {
        const int mrow = lane & 15;
        const int quad = lane >> 4;

        f32x4 acc[NT];
#pragma unroll
        for (int t = 0; t < NT; ++t) acc[t] = (f32x4){0.f, 0.f, 0.f, 0.f};

#pragma unroll
        for (int kc = 0; kc < KC; ++kc) {
            const int kof = kc * 32 + quad * 8;
            bf16x8 af = *(const bf16x8*)&xb[(wv * 16 + mrow) * KP + kof];
#pragma unroll
            for (int t = 0; t < NT; ++t) {
                bf16x8 bfr = *(const bf16x8*)&wb[(t * 16 + mrow) * KP + kof];
                acc[t] = __builtin_amdgcn_mfma_f32_16x16x32_bf16(af, bfr, acc[t], 0, 0, 0);
            }
        }

        float as_c[NT], ad_c[NT];
#pragma unroll
        for (int t = 0; t < NT; ++t) { as_c[t] = a_s[t * 16 + mrow]; ad_c[t] = a_d[t * 16 + mrow]; }

#pragma unroll
        for (int r = 0; r < 4; ++r) {
            const int node2 = base + wv * 16 + quad * 4 + r;
            float ps = 0.f, pd = 0.f;
#pragma unroll
            for (int t = 0; t < NT; ++t) {
                ps = fmaf(acc[t][r], as_c[t], ps);
                pd = fmaf(acc[t][r], ad_c[t], pd);
            }
#pragma unroll
            for (int o = 1; o < 16; o <<= 1) {
                ps += __shfl_xor(ps, o);
                pd += __shfl_xor(pd, o);
            }
            if (node2 < n) {
#pragma unroll
                for (int t = 0; t < NT; ++t)
                    hbo[(size_t)node2 * F + t * 16 + mrow] = f2bf(acc[t][r]);
                if (mrow == 0) ssdo[node2] = make_float2(ps, pd);
            }
        }
    }
}

// ---------------- final sparse layer: softmax aggregation + log_softmax ------
// S=16 lanes/node: 4 edge slots (Q=4) x 4 channel octets (NL=4). Branchless
// depth-4 phase-split gathers + degree-sorted node assignment.

template <int F, int S>
__launch_bounds__(256)
__global__ void gat_agg_k(const int* __restrict__ row_ptr, const int* __restrict__ col,
                          const int* __restrict__ perm,
                          const unsigned short* __restrict__ hb,
                          const float2* __restrict__ ssd,
                          const float* __restrict__ bias,
                          float* __restrict__ out, int n) {
    constexpr int NPW = 64 / S;          // nodes per wave
    constexpr int NL = F / 8;            // lanes per row (8 bf16 channels each)
    constexpr int Q = S / NL;            // edge slots
    constexpr int D = S / Q;             // gather depth per pass
    const int lane = threadIdx.x & 63;
    const int ls   = lane % S;           // lane in subgroup
    const int q    = ls / NL;            // edge slot
    const int cl   = ls % NL;            // channel octet index
    const int lbase = lane - ls;         // first lane of subgroup
    const int wave = (blockIdx.x * blockDim.x + threadIdx.x) >> 6;
    const int node = perm[wave * NPW + lane / S];   // degree-sorted slot -> node
    if (node >= n) return;

    const int beg = row_ptr[node];
    const int end = row_ptr[node + 1];
    const float2 sn = ssd[node];
    const float sdv = sn.y;
    float z0 = sn.x + sdv;
    z0 = (z0 > 0.f) ? z0 : NEG_SLOPE * z0;     // self-loop logit = softmax shift

    float s = 0.f;
    f32x2 acc2[4];
#pragma unroll
    for (int i = 0; i < 4; ++i) acc2[i] = (f32x2){0.f, 0.f};

    // prologue: pass-0 logit (one edge per lane)
    const int j0 = beg + ls;
    const bool vld0 = j0 < end;
    int c_cur = vld0 ? col[j0] : 0;
    float w_cur = 0.f;
    if (vld0) {
        float z = ssd[c_cur].x + sdv;
        z = (z > 0.f) ? z : NEG_SLOPE * z;
        w_cur = __expf(z - z0);
    }

    for (int b0 = beg; b0 < end; b0 += S) {
        const int jn = b0 + S + ls;
        const bool vn = jn < end;
        const int c_next = vn ? col[jn] : 0;

        s += w_cur;
        const unsigned int pk =
            ((unsigned int)f2bf(w_cur) << 17) | (unsigned int)c_cur;

        unsigned int pe[D];
#pragma unroll
        for (int t = 0; t < D; ++t)
            pe[t] = (unsigned int)__shfl((int)pk, lbase + Q * t + q);

        uint4 hv[D];
#pragma unroll
        for (int t = 0; t < D; ++t)
            hv[t] = *(const uint4*)&hb[(size_t)(pe[t] & 0x1ffffu) * F + 8 * cl];

        __builtin_amdgcn_sched_barrier(0);

        float w_next = 0.f;
        if (vn) {
            float z = ssd[c_next].x + sdv;
            z = (z > 0.f) ? z : NEG_SLOPE * z;
            w_next = __expf(z - z0);
        }

#pragma unroll
        for (int t = 0; t < D; ++t) {
            const float wt = __uint_as_float((pe[t] >> 17) << 16);
            f32x2 p;
            p.x = bf_lo(hv[t].x); p.y = bf_hi(hv[t].x); acc2[0] += p * wt;
            p.x = bf_lo(hv[t].y); p.y = bf_hi(hv[t].y); acc2[1] += p * wt;
            p.x = bf_lo(hv[t].z); p.y = bf_hi(hv[t].z); acc2[2] += p * wt;
            p.x = bf_lo(hv[t].w); p.y = bf_hi(hv[t].w); acc2[3] += p * wt;
        }
        c_cur = c_next;
        w_cur = w_next;
    }

#pragma unroll
    for (int o = S / 2; o; o >>= 1) s += __shfl_xor(s, o);
    float val[8] = {acc2[0].x, acc2[0].y, acc2[1].x, acc2[1].y,
                    acc2[2].x, acc2[2].y, acc2[3].x, acc2[3].y};
#pragma unroll
    for (int o = NL; o < S; o <<= 1) {
#pragma unroll
        for (int i = 0; i < 8; ++i) val[i] += __shfl_xor(val[i], o);
    }

    const float inv = 1.f / (s + 1e-16f);
#pragma unroll
    for (int i = 0; i < 8; ++i)
        val[i] = val[i] * inv + bias[8 * cl + i];

    // log_softmax over F channels
    float lm = val[0];
#pragma unroll
    for (int i = 1; i < 8; ++i) lm = fmaxf(lm, val[i]);
#pragma unroll
    for (int o = 1; o < NL; o <<= 1) lm = fmaxf(lm, __shfl_xor(lm, o));
    float ex = 0.f;
#pragma unroll
    for (int i = 0; i < 8; ++i) ex += __expf(val[i] - lm);
#pragma unroll
    for (int o = 1; o < NL; o <<= 1) ex += __shfl_xor(ex, o);
    const float lse = lm + __logf(ex);
#pragma unroll
    for (int i = 0; i < 8; ++i) val[i] -= lse;

    if (q == 0) {
        float4 v0 = make_float4(val[0], val[1], val[2], val[3]);
        float4 v1 = make_float4(val[4], val[5], val[6], val[7]);
        *(float4*)&out[(size_t)node * F + 8 * cl] = v0;
        *(float4*)&out[(size_t)node * F + 8 * cl + 4] = v1;
    }
}

// ---------------- launch ----------------

extern "C" void kernel_launch(void* const* d_in, const int* in_sizes, int n_in,
                              void* d_out, int out_size, void* d_ws, size_t ws_size,
                              hipStream_t stream) {
    const float* x  = (const float*)d_in[0];
    const int*   ei = (const int*)d_in[1];
    const float* W1 = (const float*)d_in[2];
    const float* a1s = (const float*)d_in[3];
    const float* a1d = (const float*)d_in[4];
    const float* b1  = (const float*)d_in[5];
    const float* W2 = (const float*)d_in[6];
    const float* a2s = (const float*)d_in[7];
    const float* a2d = (const float*)d_in[8];
    const float* b2  = (const float*)d_in[9];
    const float* W3 = (const float*)d_in[10];
    const float* a3s = (const float*)d_in[11];
    const float* a3d = (const float*)d_in[12];
    const float* b3  = (const float*)d_in[13];

    const int N = in_sizes[0] / 128;
    const int E = in_sizes[1] / 2;
    const int NBK = (N + 127) / 128;
    const int B = BIN_BLOCKS;
    const int GB = (N + 63) / 64;        // 64-node tiles

    char* wp = (char*)d_ws;
    auto alloc = [&](size_t bytes) -> void* {
        void* p = wp;
        wp += (bytes + 255) & ~(size_t)255;
        return p;
    };
    int* row_ptr = (int*)alloc((size_t)(N + 1) * 4);
    int* col     = (int*)alloc((size_t)(E + N) * 4);
    int* perm    = (int*)alloc((size_t)GB * 64 * 4);
    unsigned short* hb1 = (unsigned short*)alloc((size_t)N * 64 * 2);
    unsigned short* hb2 = (unsigned short*)alloc((size_t)N * 64 * 2);
    unsigned short* hb3 = (unsigned short*)alloc((size_t)N * 32 * 2);
    float2* ssd1 = (float2*)alloc((size_t)N * 8);
    float2* ssd2 = (float2*)alloc((size_t)N * 8);
    float2* ssd3 = (float2*)alloc((size_t)N * 8);
    int* btot   = (int*)alloc((size_t)NBK * 4);
    int* blkoff = (int*)alloc((size_t)NBK * B * 4);
    int* obk    = (int*)alloc((size_t)(NBK + 1) * 4);
    int* eb     = (int*)alloc((size_t)E * 4);

    const int chunk = (E + B - 1) / B;

    zero_k<<<(NBK + 255) / 256, 256, 0, stream>>>(btot, NBK);
    bin_hist_k<<<B, 256, 0, stream>>>(ei + E, E, btot, blkoff, NBK, chunk);
    scan_small_k<<<1, 256, 0, stream>>>(btot, obk, NBK);
    bin_scatter_k<<<B, 256, 0, stream>>>(ei, E, obk, blkoff, eb, NBK, chunk);
    bucket_build_k<<<NBK, 256, 0, stream>>>(eb, obk, row_ptr, col, N, NBK);
    tile_sort_k<<<(GB + 3) / 4, 256, 0, stream>>>(row_ptr, perm, N, GB);

    // layer 1 GEMM: 128 -> 64 (fp32 x input)
    gemm_mfma_k<128, 64><<<GB, 256, 0, stream>>>(x, W1, a1s, a1d, hb1, ssd1, N);
    // fused: agg layer1 (relu) + GEMM layer2 64 -> 64
    agg_gemm_k<64, 64><<<GB, 512, 0, stream>>>(row_ptr, col, perm, hb1, ssd1, b1,
                                               W2, a2s, a2d, hb2, ssd2, N);
    // fused: agg layer2 (relu) + GEMM layer3 64 -> 32
    agg_gemm_k<64, 32><<<GB, 512, 0, stream>>>(row_ptr, col, perm, hb2, ssd2, b2,
                                               W3, a3s, a3d, hb3, ssd3, N);
    // final agg + log_softmax (fp32 out)
    gat_agg_k<32, 16><<<(N + 15) / 16, 256, 0, stream>>>(
        row_ptr, col, perm, hb3, ssd3, b3, (float*)d_out, N);
}

// Round 7
// 288.791 us; speedup vs baseline: 1.0007x; 1.0007x over previous
//
#include <hip/hip_runtime.h>
#include <cstddef>
#include <cstdint>

#define NEG_SLOPE 0.2f

__device__ __forceinline__ unsigned short f2bf(float f) {
    unsigned int u = __float_as_uint(f);
    u = (u + 0x7fff + ((u >> 16) & 1)) >> 16;   // round-to-nearest-even
    return (unsigned short)u;
}
__device__ __forceinline__ float bf_lo(unsigned int u) { return __uint_as_float(u << 16); }
__device__ __forceinline__ float bf_hi(unsigned int u) { return __uint_as_float(u & 0xffff0000u); }

typedef __attribute__((ext_vector_type(8))) short bf16x8;   // MFMA A/B frag (4 VGPRs)
typedef __attribute__((ext_vector_type(4))) float f32x4;    // MFMA C/D frag
typedef __attribute__((ext_vector_type(2))) float f32x2;    // v_pk_fma_f32 pair

// ---------------- binned CSR build ----------------
// Bucket = dst >> 7 (128 nodes/bucket). Edges packed (src<<7)|dstLow (src<2^17).

constexpr int BIN_BLOCKS = 256;
constexpr int MAX_NBK = 1024;            // supports N <= 131072 (= packing limit)

__global__ __launch_bounds__(256) void zero_k(int* __restrict__ p, int n) {
    int i = blockIdx.x * blockDim.x + threadIdx.x;
    if (i < n) p[i] = 0;
}

__global__ __launch_bounds__(256) void bin_hist_k(const int* __restrict__ dst, int E,
                                                  int* __restrict__ btot,
                                                  int* __restrict__ blkoff,
                                                  int nbk, int chunk) {
    __shared__ int hist[MAX_NBK];
    for (int i = threadIdx.x; i < nbk; i += 256) hist[i] = 0;
    __syncthreads();
    const int lo = blockIdx.x * chunk;
    const int hi = min(lo + chunk, E);
    for (int e = lo + threadIdx.x; e < hi; e += 256)
        atomicAdd(&hist[dst[e] >> 7], 1);
    __syncthreads();
    const int B = gridDim.x;
    for (int i = threadIdx.x; i < nbk; i += 256)
        blkoff[i * B + blockIdx.x] = atomicAdd(&btot[i], hist[i]);
}

// exclusive scan of nbk (<=1024) bucket totals -> obk[nbk+1]  (wave-parallel)
__global__ __launch_bounds__(256) void scan_small_k(const int* __restrict__ btot,
                                                    int* __restrict__ obk, int nbk) {
    __shared__ int sh[MAX_NBK];
    const int tid = threadIdx.x;
    for (int i = tid; i < nbk; i += 256) sh[i] = btot[i];
    __syncthreads();
    if (tid < 64) {
        int run = 0;
        for (int b0 = 0; b0 < nbk; b0 += 64) {
            const int i = b0 + tid;
            int v = (i < nbk) ? sh[i] : 0;
            int inc = v;
#pragma unroll
            for (int o = 1; o < 64; o <<= 1) {
                int u = __shfl_up(inc, o);
                if (tid >= o) inc += u;
            }
            if (i < nbk) sh[i] = run + inc - v;       // exclusive
            run += __shfl(inc, 63);
        }
        if (tid == 0) obk[nbk] = run;                 // total edge count
    }
    __syncthreads();
    for (int i = tid; i < nbk; i += 256) obk[i] = sh[i];
}

__global__ __launch_bounds__(256) void bin_scatter_k(const int* __restrict__ ei, int E,
                                                     const int* __restrict__ obk,
                                                     const int* __restrict__ blkoff,
                                                     int* __restrict__ eb, int nbk,
                                                     int chunk) {
    __shared__ int cur[MAX_NBK];
    __shared__ int off_s[MAX_NBK];
    const int B = gridDim.x;
    for (int i = threadIdx.x; i < nbk; i += 256) {
        cur[i] = 0;
        off_s[i] = obk[i] + blkoff[i * B + blockIdx.x];
    }
    __syncthreads();
    const int lo = blockIdx.x * chunk;
    const int hi = min(lo + chunk, E);
    for (int e = lo + threadIdx.x; e < hi; e += 256) {
        int s = ei[e];
        int d = ei[E + e];
        int b = d >> 7;
        int idx = atomicAdd(&cur[b], 1);
        eb[off_s[b] + idx] = (s << 7) | (d & 127);
    }
}

__global__ __launch_bounds__(256) void bucket_build_k(const int* __restrict__ eb,
                                                      const int* __restrict__ obk,
                                                      int* __restrict__ row_ptr,
                                                      int* __restrict__ col,
                                                      int n, int nbk) {
    __shared__ int c[128];
    __shared__ int rp[128];
    const int b = blockIdx.x;
    const int t = threadIdx.x;
    const int beg = obk[b];
    const int end = obk[b + 1];
    const int bbase = beg + b * 128;     // preceding buckets are full (128 loops each)
    if (t < 128) c[t] = 1;               // self-loop pre-count
    __syncthreads();
    for (int i = beg + t; i < end; i += 256)
        atomicAdd(&c[eb[i] & 127], 1);
    __syncthreads();
    if (t < 64) {                        // exclusive scan of 128 degrees (wave 0)
        int v0 = c[2 * t], v1 = c[2 * t + 1];
        int pair = v0 + v1;
        int inc = pair;
        for (int o = 1; o < 64; o <<= 1) {
            int u = __shfl_up(inc, o);
            if (t >= o) inc += u;
        }
        int ex = inc - pair;
        rp[2 * t] = bbase + ex;
        rp[2 * t + 1] = bbase + ex + v0;
    }
    __syncthreads();
    const int node = b * 128 + t;
    if (t < 128 && node < n) {
        row_ptr[node] = rp[t];
        col[rp[t]] = node;               // self-loop in slot 0
    }
    if (b == 0 && t == 0) row_ptr[n] = obk[nbk] + n;
    __syncthreads();
    if (t < 128) c[t] = 1;
    __syncthreads();
    for (int i = beg + t; i < end; i += 256) {
        int p = eb[i];
        int dl = p & 127;
        int idx = atomicAdd(&c[dl], 1);
        col[rp[dl] + idx] = p >> 7;
    }
}

// ---------------- degree-sorted tile permutation -----------------------------
// One wave per 64-node tile: bitonic-sort lanes by degree so subgroups sharing
// a wave in the agg kernels get similar-degree nodes. perm[slot] = node id.

__global__ __launch_bounds__(256) void tile_sort_k(const int* __restrict__ row_ptr,
                                                   int* __restrict__ perm,
                                                   int n, int ntiles) {
    const int wv = threadIdx.x >> 6;
    const int lane = threadIdx.x & 63;
    const int tile = blockIdx.x * 4 + wv;
    if (tile >= ntiles) return;
    const int node = tile * 64 + lane;
    const int deg = (node < n) ? (row_ptr[node + 1] - row_ptr[node]) : 0x3fffff;
    int key = (deg << 6) | lane;         // composite key, all distinct
    for (int k = 2; k <= 64; k <<= 1) {
        for (int j = k >> 1; j > 0; j >>= 1) {
            const int pkey = __shfl_xor(key, j);
            const bool up = ((lane & k) == 0);
            const bool keep_min = (((lane & j) == 0) == up);
            key = keep_min ? min(key, pkey) : max(key, pkey);
        }
    }
    perm[tile * 64 + lane] = tile * 64 + (key & 63);
}

// ---------------- layer 1 dense: fp32 x -> MFMA bf16 GEMM + attention dots ----

template <int K, int F>
__launch_bounds__(256)
__global__ void gemm_mfma_k(const float* __restrict__ x, const float* __restrict__ W,
                            const float* __restrict__ a_s, const float* __restrict__ a_d,
                            unsigned short* __restrict__ hb, float2* __restrict__ ssd,
                            int n) {
    constexpr int MT = 64;               // rows per block
    constexpr int KP = K + 8;            // padded inner stride (bf16 elems)
    constexpr int NT = F / 16;           // n-tiles per wave
    constexpr int KC = K / 32;           // k-steps

    __shared__ unsigned short xb[MT * KP];
    __shared__ unsigned short wb[F * KP];

    const int tid = threadIdx.x;
    const int lane = tid & 63;
    const int wv = tid >> 6;             // wave id 0..3
    const int base = blockIdx.x * MT;

    for (int i = tid; i < MT * K / 4; i += 256) {
        int row = i / (K / 4);
        int c4 = i % (K / 4);
        float4 v = make_float4(0.f, 0.f, 0.f, 0.f);
        if (base + row < n)
            v = *(const float4*)&x[(size_t)(base + row) * K + 4 * c4];
        ushort4 b;
        b.x = f2bf(v.x); b.y = f2bf(v.y); b.z = f2bf(v.z); b.w = f2bf(v.w);
        *(ushort4*)&xb[row * KP + 4 * c4] = b;
    }
    // W staging, k-contiguous ushort4 stores (lane stride 2*KP B -> ~8 banks)
    for (int i = tid; i < K * F / 4; i += 256) {
        int nn = i % F;
        int k4 = i / F;
        ushort4 b;
        b.x = f2bf(W[(size_t)(4 * k4 + 0) * F + nn]);
        b.y = f2bf(W[(size_t)(4 * k4 + 1) * F + nn]);
        b.z = f2bf(W[(size_t)(4 * k4 + 2) * F + nn]);
        b.w = f2bf(W[(size_t)(4 * k4 + 3) * F + nn]);
        *(ushort4*)&wb[nn * KP + 4 * k4] = b;
    }
    __syncthreads();

    const int mrow = lane & 15;
    const int quad = lane >> 4;

    f32x4 acc[NT];
#pragma unroll
    for (int t = 0; t < NT; ++t) acc[t] = (f32x4){0.f, 0.f, 0.f, 0.f};

#pragma unroll
    for (int kc = 0; kc < KC; ++kc) {
        const int kof = kc * 32 + quad * 8;
        bf16x8 af = *(const bf16x8*)&xb[(wv * 16 + mrow) * KP + kof];
#pragma unroll
        for (int t = 0; t < NT; ++t) {
            bf16x8 bfr = *(const bf16x8*)&wb[(t * 16 + mrow) * KP + kof];
            acc[t] = __builtin_amdgcn_mfma_f32_16x16x32_bf16(af, bfr, acc[t], 0, 0, 0);
        }
    }

    float as_c[NT], ad_c[NT];
#pragma unroll
    for (int t = 0; t < NT; ++t) { as_c[t] = a_s[t * 16 + mrow]; ad_c[t] = a_d[t * 16 + mrow]; }

#pragma unroll
    for (int r = 0; r < 4; ++r) {
        const int node = base + wv * 16 + quad * 4 + r;
        float ps = 0.f, pd = 0.f;
#pragma unroll
        for (int t = 0; t < NT; ++t) {
            ps = fmaf(acc[t][r], as_c[t], ps);
            pd = fmaf(acc[t][r], ad_c[t], pd);
        }
#pragma unroll
        for (int o = 1; o < 16; o <<= 1) {
            ps += __shfl_xor(ps, o);
            pd += __shfl_xor(pd, o);
        }
        if (node < n) {
#pragma unroll
            for (int t = 0; t < NT; ++t)
                hb[(size_t)node * F + t * 16 + mrow] = f2bf(acc[t][r]);
            if (mrow == 0) ssd[node] = make_float2(ps, pd);
        }
    }
}

// ---------------- fused agg(layer i) + gemm(layer i+1) -----------------------
// 256 threads = 4 waves. S=4 lanes/node (16 channels/lane, 2 uint4 per edge):
// all 4 waves aggregate the 64-row tile (no idle waves), then ALL 4 waves run
// the MFMA. 4-wave blocks pack up to 8/CU (LDS 18.4KB) -> occupancy ceiling
// 32 waves/CU vs the old 8-wave structure's ~14. Hot loop branchless +
// phase-split (4 shfl -> 8 gathers -> sched_barrier -> logit chain -> consume).

template <int K, int F>
__launch_bounds__(256)
__global__ void agg_gemm_k(const int* __restrict__ row_ptr, const int* __restrict__ col,
                           const int* __restrict__ perm,
                           const unsigned short* __restrict__ hbi,
                           const float2* __restrict__ ssdi,
                           const float* __restrict__ bias,
                           const float* __restrict__ W,
                           const float* __restrict__ a_s, const float* __restrict__ a_d,
                           unsigned short* __restrict__ hbo, float2* __restrict__ ssdo,
                           int n) {
    static_assert(K == 64, "agg phase assumes 64 input channels");
    constexpr int S = 4;                 // lanes per node (16 channels each)
    constexpr int MT = 64;               // nodes (= GEMM rows) per block
    constexpr int KP = K + 8;
    constexpr int NT = F / 16;
    constexpr int KC = K / 32;

    __shared__ unsigned short xb[MT * KP];
    __shared__ unsigned short wb[F * KP];

    const int tid = threadIdx.x;
    const int lane = tid & 63;
    const int wv = tid >> 6;             // 0..3
    const int base = blockIdx.x * MT;

    // stage W (read before phase 1; consumed after the single barrier)
    for (int i = tid; i < K * F / 4; i += 256) {
        int nn = i % F;
        int k4 = i / F;
        ushort4 b;
        b.x = f2bf(W[(size_t)(4 * k4 + 0) * F + nn]);
        b.y = f2bf(W[(size_t)(4 * k4 + 1) * F + nn]);
        b.z = f2bf(W[(size_t)(4 * k4 + 2) * F + nn]);
        b.w = f2bf(W[(size_t)(4 * k4 + 3) * F + nn]);
        *(ushort4*)&wb[nn * KP + 4 * k4] = b;
    }

    // ---- phase 1: softmax aggregation, 4 lanes per node (degree-sorted) ----
    const int ls = lane & (S - 1);       // lane in subgroup (channel 16*ls..)
    const int lbase = lane - ls;
    const int nl = tid >> 2;             // sorted slot 0..63
    const int pnode = perm[base + nl];   // node this subgroup aggregates
    const int slot = pnode - base;       // its row in the A-tile (bijective)

    float val[16];
#pragma unroll
    for (int i = 0; i < 16; ++i) val[i] = 0.f;

    if (pnode < n) {
        const int beg = row_ptr[pnode];
        const int end = row_ptr[pnode + 1];
        const float2 sn = ssdi[pnode];
        const float sdv = sn.y;
        float z0 = sn.x + sdv;
        z0 = (z0 > 0.f) ? z0 : NEG_SLOPE * z0;   // self-loop logit = softmax shift

        float s = 0.f;
        f32x2 acc2[8];
#pragma unroll
        for (int i = 0; i < 8; ++i) acc2[i] = (f32x2){0.f, 0.f};

        // prologue: pass-0 logit
        const int j0 = beg + ls;
        const bool vld0 = j0 < end;
        int c_cur = vld0 ? col[j0] : 0;
        float w_cur = 0.f;
        if (vld0) {
            float z = ssdi[c_cur].x + sdv;
            z = (z > 0.f) ? z : NEG_SLOPE * z;
            w_cur = __expf(z - z0);
        }

        for (int b0 = beg; b0 < end; b0 += S) {
            const int jn = b0 + S + ls;
            const bool vn = jn < end;
            const int c_next = vn ? col[jn] : 0;     // issued before gathers

            s += w_cur;
            const unsigned int pk =
                ((unsigned int)f2bf(w_cur) << 17) | (unsigned int)c_cur;

            // phase A: cross-lane moves (pk of the 4 edges of this node)
            unsigned int pe[4];
#pragma unroll
            for (int t = 0; t < 4; ++t)
                pe[t] = (unsigned int)__shfl((int)pk, lbase + t);

            // phase B: 8 gathers (2 per edge) issued back-to-back
            uint4 hv[8];
#pragma unroll
            for (int t = 0; t < 4; ++t) {
                const size_t off = (size_t)(pe[t] & 0x1ffffu) * K + 16 * ls;
                hv[2 * t]     = *(const uint4*)&hbi[off];
                hv[2 * t + 1] = *(const uint4*)&hbi[off + 8];
            }

            __builtin_amdgcn_sched_barrier(0);   // keep consume out of the load pack

            // next-pass logit chain overlaps the in-flight gathers
            float w_next = 0.f;
            if (vn) {
                float z = ssdi[c_next].x + sdv;
                z = (z > 0.f) ? z : NEG_SLOPE * z;
                w_next = __expf(z - z0);
            }

            // phase C: consume (wt == 0 for tail slots -> zero contribution)
#pragma unroll
            for (int t = 0; t < 4; ++t) {
                const float wt = __uint_as_float((pe[t] >> 17) << 16);
                f32x2 p;
                p.x = bf_lo(hv[2 * t].x); p.y = bf_hi(hv[2 * t].x); acc2[0] += p * wt;
                p.x = bf_lo(hv[2 * t].y); p.y = bf_hi(hv[2 * t].y); acc2[1] += p * wt;
                p.x = bf_lo(hv[2 * t].z); p.y = bf_hi(hv[2 * t].z); acc2[2] += p * wt;
                p.x = bf_lo(hv[2 * t].w); p.y = bf_hi(hv[2 * t].w); acc2[3] += p * wt;
                p.x = bf_lo(hv[2 * t + 1].x); p.y = bf_hi(hv[2 * t + 1].x); acc2[4] += p * wt;
                p.x = bf_lo(hv[2 * t + 1].y); p.y = bf_hi(hv[2 * t + 1].y); acc2[5] += p * wt;
                p.x = bf_lo(hv[2 * t + 1].z); p.y = bf_hi(hv[2 * t + 1].z); acc2[6] += p * wt;
                p.x = bf_lo(hv[2 * t + 1].w); p.y = bf_hi(hv[2 * t + 1].w); acc2[7] += p * wt;
            }
            c_cur = c_next;
            w_cur = w_next;
        }
        // reduce s over the 4-lane subgroup
        s += __shfl_xor(s, 1);
        s += __shfl_xor(s, 2);
        const float inv = 1.f / (s + 1e-16f);
#pragma unroll
        for (int i = 0; i < 8; ++i) {
            val[2 * i]     = acc2[i].x;
            val[2 * i + 1] = acc2[i].y;
        }
#pragma unroll
        for (int i = 0; i < 16; ++i)
            val[i] = fmaxf(val[i] * inv + bias[16 * ls + i], 0.f);   // bias + relu
    }
    {   // bf16 row (16 channels/lane) into this node's A-tile slot
        ushort4 p0, p1, p2, p3;
        p0.x = f2bf(val[0]);  p0.y = f2bf(val[1]);  p0.z = f2bf(val[2]);  p0.w = f2bf(val[3]);
        p1.x = f2bf(val[4]);  p1.y = f2bf(val[5]);  p1.z = f2bf(val[6]);  p1.w = f2bf(val[7]);
        p2.x = f2bf(val[8]);  p2.y = f2bf(val[9]);  p2.z = f2bf(val[10]); p2.w = f2bf(val[11]);
        p3.x = f2bf(val[12]); p3.y = f2bf(val[13]); p3.z = f2bf(val[14]); p3.w = f2bf(val[15]);
        *(ushort4*)&xb[slot * KP + 16 * ls]      = p0;
        *(ushort4*)&xb[slot * KP + 16 * ls + 4]  = p1;
        *(ushort4*)&xb[slot * KP + 16 * ls + 8]  = p2;
        *(ushort4*)&xb[slot * KP + 16 * ls + 12] = p3;
    }

    __syncthreads();

    // ---- phase 2: h = o @ W + fused attention dots (all 4 waves) ----
    {
        const int mrow = lane & 15;
        const int quad = lane >> 4;

        f32x4 acc[NT];
#pragma unroll
        for (int t = 0; t < NT; ++t) acc[t] = (f32x4){0.f, 0.f, 0.f, 0.f};

#pragma unroll
        for (int kc = 0; kc < KC; ++kc) {
            const int kof = kc * 32 + quad * 8;
            bf16x8 af = *(const bf16x8*)&xb[(wv * 16 + mrow) * KP + kof];
#pragma unroll
            for (int t = 0; t < NT; ++t) {
                bf16x8 bfr = *(const bf16x8*)&wb[(t * 16 + mrow) * KP + kof];
                acc[t] = __builtin_amdgcn_mfma_f32_16x16x32_bf16(af, bfr, acc[t], 0, 0, 0);
            }
        }

        float as_c[NT], ad_c[NT];
#pragma unroll
        for (int t = 0; t < NT; ++t) { as_c[t] = a_s[t * 16 + mrow]; ad_c[t] = a_d[t * 16 + mrow]; }

#pragma unroll
        for (int r = 0; r < 4; ++r) {
            const int node2 = base + wv * 16 + quad * 4 + r;
            float ps = 0.f, pd = 0.f;
#pragma unroll
            for (int t = 0; t < NT; ++t) {
                ps = fmaf(acc[t][r], as_c[t], ps);
                pd = fmaf(acc[t][r], ad_c[t], pd);
            }
#pragma unroll
            for (int o = 1; o < 16; o <<= 1) {
                ps += __shfl_xor(ps, o);
                pd += __shfl_xor(pd, o);
            }
            if (node2 < n) {
#pragma unroll
                for (int t = 0; t < NT; ++t)
                    hbo[(size_t)node2 * F + t * 16 + mrow] = f2bf(acc[t][r]);
                if (mrow == 0) ssdo[node2] = make_float2(ps, pd);
            }
        }
    }
}

// ---------------- final sparse layer: softmax aggregation + log_softmax ------
// S=16 lanes/node: 4 edge slots (Q=4) x 4 channel octets (NL=4). Branchless
// depth-4 phase-split gathers + degree-sorted node assignment.

template <int F, int S>
__launch_bounds__(256)
__global__ void gat_agg_k(const int* __restrict__ row_ptr, const int* __restrict__ col,
                          const int* __restrict__ perm,
                          const unsigned short* __restrict__ hb,
                          const float2* __restrict__ ssd,
                          const float* __restrict__ bias,
                          float* __restrict__ out, int n) {
    constexpr int NPW = 64 / S;          // nodes per wave
    constexpr int NL = F / 8;            // lanes per row (8 bf16 channels each)
    constexpr int Q = S / NL;            // edge slots
    constexpr int D = S / Q;             // gather depth per pass
    const int lane = threadIdx.x & 63;
    const int ls   = lane % S;           // lane in subgroup
    const int q    = ls / NL;            // edge slot
    const int cl   = ls % NL;            // channel octet index
    const int lbase = lane - ls;         // first lane of subgroup
    const int wave = (blockIdx.x * blockDim.x + threadIdx.x) >> 6;
    const int node = perm[wave * NPW + lane / S];   // degree-sorted slot -> node
    if (node >= n) return;

    const int beg = row_ptr[node];
    const int end = row_ptr[node + 1];
    const float2 sn = ssd[node];
    const float sdv = sn.y;
    float z0 = sn.x + sdv;
    z0 = (z0 > 0.f) ? z0 : NEG_SLOPE * z0;     // self-loop logit = softmax shift

    float s = 0.f;
    f32x2 acc2[4];
#pragma unroll
    for (int i = 0; i < 4; ++i) acc2[i] = (f32x2){0.f, 0.f};

    // prologue: pass-0 logit (one edge per lane)
    const int j0 = beg + ls;
    const bool vld0 = j0 < end;
    int c_cur = vld0 ? col[j0] : 0;
    float w_cur = 0.f;
    if (vld0) {
        float z = ssd[c_cur].x + sdv;
        z = (z > 0.f) ? z : NEG_SLOPE * z;
        w_cur = __expf(z - z0);
    }

    for (int b0 = beg; b0 < end; b0 += S) {
        const int jn = b0 + S + ls;
        const bool vn = jn < end;
        const int c_next = vn ? col[jn] : 0;

        s += w_cur;
        const unsigned int pk =
            ((unsigned int)f2bf(w_cur) << 17) | (unsigned int)c_cur;

        unsigned int pe[D];
#pragma unroll
        for (int t = 0; t < D; ++t)
            pe[t] = (unsigned int)__shfl((int)pk, lbase + Q * t + q);

        uint4 hv[D];
#pragma unroll
        for (int t = 0; t < D; ++t)
            hv[t] = *(const uint4*)&hb[(size_t)(pe[t] & 0x1ffffu) * F + 8 * cl];

        __builtin_amdgcn_sched_barrier(0);

        float w_next = 0.f;
        if (vn) {
            float z = ssd[c_next].x + sdv;
            z = (z > 0.f) ? z : NEG_SLOPE * z;
            w_next = __expf(z - z0);
        }

#pragma unroll
        for (int t = 0; t < D; ++t) {
            const float wt = __uint_as_float((pe[t] >> 17) << 16);
            f32x2 p;
            p.x = bf_lo(hv[t].x); p.y = bf_hi(hv[t].x); acc2[0] += p * wt;
            p.x = bf_lo(hv[t].y); p.y = bf_hi(hv[t].y); acc2[1] += p * wt;
            p.x = bf_lo(hv[t].z); p.y = bf_hi(hv[t].z); acc2[2] += p * wt;
            p.x = bf_lo(hv[t].w); p.y = bf_hi(hv[t].w); acc2[3] += p * wt;
        }
        c_cur = c_next;
        w_cur = w_next;
    }

#pragma unroll
    for (int o = S / 2; o; o >>= 1) s += __shfl_xor(s, o);
    float val[8] = {acc2[0].x, acc2[0].y, acc2[1].x, acc2[1].y,
                    acc2[2].x, acc2[2].y, acc2[3].x, acc2[3].y};
#pragma unroll
    for (int o = NL; o < S; o <<= 1) {
#pragma unroll
        for (int i = 0; i < 8; ++i) val[i] += __shfl_xor(val[i], o);
    }

    const float inv = 1.f / (s + 1e-16f);
#pragma unroll
    for (int i = 0; i < 8; ++i)
        val[i] = val[i] * inv + bias[8 * cl + i];

    // log_softmax over F channels
    float lm = val[0];
#pragma unroll
    for (int i = 1; i < 8; ++i) lm = fmaxf(lm, val[i]);
#pragma unroll
    for (int o = 1; o < NL; o <<= 1) lm = fmaxf(lm, __shfl_xor(lm, o));
    float ex = 0.f;
#pragma unroll
    for (int i = 0; i < 8; ++i) ex += __expf(val[i] - lm);
#pragma unroll
    for (int o = 1; o < NL; o <<= 1) ex += __shfl_xor(ex, o);
    const float lse = lm + __logf(ex);
#pragma unroll
    for (int i = 0; i < 8; ++i) val[i] -= lse;

    if (q == 0) {
        float4 v0 = make_float4(val[0], val[1], val[2], val[3]);
        float4 v1 = make_float4(val[4], val[5], val[6], val[7]);
        *(float4*)&out[(size_t)node * F + 8 * cl] = v0;
        *(float4*)&out[(size_t)node * F + 8 * cl + 4] = v1;
    }
}

// ---------------- launch ----------------

extern "C" void kernel_launch(void* const* d_in, const int* in_sizes, int n_in,
                              void* d_out, int out_size, void* d_ws, size_t ws_size,
                              hipStream_t stream) {
    const float* x  = (const float*)d_in[0];
    const int*   ei = (const int*)d_in[1];
    const float* W1 = (const float*)d_in[2];
    const float* a1s = (const float*)d_in[3];
    const float* a1d = (const float*)d_in[4];
    const float* b1  = (const float*)d_in[5];
    const float* W2 = (const float*)d_in[6];
    const float* a2s = (const float*)d_in[7];
    const float* a2d = (const float*)d_in[8];
    const float* b2  = (const float*)d_in[9];
    const float* W3 = (const float*)d_in[10];
    const float* a3s = (const float*)d_in[11];
    const float* a3d = (const float*)d_in[12];
    const float* b3  = (const float*)d_in[13];

    const int N = in_sizes[0] / 128;
    const int E = in_sizes[1] / 2;
    const int NBK = (N + 127) / 128;
    const int B = BIN_BLOCKS;
    const int GB = (N + 63) / 64;        // 64-node tiles

    char* wp = (char*)d_ws;
    auto alloc = [&](size_t bytes) -> void* {
        void* p = wp;
        wp += (bytes + 255) & ~(size_t)255;
        return p;
    };
    int* row_ptr = (int*)alloc((size_t)(N + 1) * 4);
    int* col     = (int*)alloc((size_t)(E + N) * 4);
    int* perm    = (int*)alloc((size_t)GB * 64 * 4);
    unsigned short* hb1 = (unsigned short*)alloc((size_t)N * 64 * 2);
    unsigned short* hb2 = (unsigned short*)alloc((size_t)N * 64 * 2);
    unsigned short* hb3 = (unsigned short*)alloc((size_t)N * 32 * 2);
    float2* ssd1 = (float2*)alloc((size_t)N * 8);
    float2* ssd2 = (float2*)alloc((size_t)N * 8);
    float2* ssd3 = (float2*)alloc((size_t)N * 8);
    int* btot   = (int*)alloc((size_t)NBK * 4);
    int* blkoff = (int*)alloc((size_t)NBK * B * 4);
    int* obk    = (int*)alloc((size_t)(NBK + 1) * 4);
    int* eb     = (int*)alloc((size_t)E * 4);

    const int chunk = (E + B - 1) / B;

    zero_k<<<(NBK + 255) / 256, 256, 0, stream>>>(btot, NBK);
    bin_hist_k<<<B, 256, 0, stream>>>(ei + E, E, btot, blkoff, NBK, chunk);
    scan_small_k<<<1, 256, 0, stream>>>(btot, obk, NBK);
    bin_scatter_k<<<B, 256, 0, stream>>>(ei, E, obk, blkoff, eb, NBK, chunk);
    bucket_build_k<<<NBK, 256, 0, stream>>>(eb, obk, row_ptr, col, N, NBK);
    tile_sort_k<<<(GB + 3) / 4, 256, 0, stream>>>(row_ptr, perm, N, GB);

    // layer 1 GEMM: 128 -> 64 (fp32 x input)
    gemm_mfma_k<128, 64><<<GB, 256, 0, stream>>>(x, W1, a1s, a1d, hb1, ssd1, N);
    // fused: agg layer1 (relu) + GEMM layer2 64 -> 64
    agg_gemm_k<64, 64><<<GB, 256, 0, stream>>>(row_ptr, col, perm, hb1, ssd1, b1,
                                               W2, a2s, a2d, hb2, ssd2, N);
    // fused: agg layer2 (relu) + GEMM layer3 64 -> 32
    agg_gemm_k<64, 32><<<GB, 256, 0, stream>>>(row_ptr, col, perm, hb2, ssd2, b2,
                                               W3, a3s, a3d, hb3, ssd3, N);
    // final agg + log_softmax (fp32 out)
    gat_agg_k<32, 16><<<(N + 15) / 16, 256, 0, stream>>>(
        row_ptr, col, perm, hb3, ssd3, b3, (float*)d_out, N);
}

// Round 8
// 288.701 us; speedup vs baseline: 1.0010x; 1.0003x over previous
//
#include <hip/hip_runtime.h>
#include <cstddef>
#include <cstdint>

#define NEG_SLOPE 0.2f

__device__ __forceinline__ unsigned short f2bf(float f) {
    unsigned int u = __float_as_uint(f);
    u = (u + 0x7fff + ((u >> 16) & 1)) >> 16;   // round-to-nearest-even
    return (unsigned short)u;
}
__device__ __forceinline__ float bf_lo(unsigned int u) { return __uint_as_float(u << 16); }
__device__ __forceinline__ float bf_hi(unsigned int u) { return __uint_as_float(u & 0xffff0000u); }

typedef __attribute__((ext_vector_type(8))) short bf16x8;   // MFMA A/B frag (4 VGPRs)
typedef __attribute__((ext_vector_type(4))) float f32x4;    // MFMA C/D frag
typedef __attribute__((ext_vector_type(2))) float f32x2;    // v_pk_fma_f32 pair

// ---------------- binned CSR build ----------------
// Bucket = dst >> 7 (128 nodes/bucket). Edges packed (src<<7)|dstLow (src<2^17).

constexpr int BIN_BLOCKS = 256;
constexpr int MAX_NBK = 1024;            // supports N <= 131072 (= packing limit)

__global__ __launch_bounds__(256) void zero_k(int* __restrict__ p, int n) {
    int i = blockIdx.x * blockDim.x + threadIdx.x;
    if (i < n) p[i] = 0;
}

__global__ __launch_bounds__(256) void bin_hist_k(const int* __restrict__ dst, int E,
                                                  int* __restrict__ btot,
                                                  int* __restrict__ blkoff,
                                                  int nbk, int chunk) {
    __shared__ int hist[MAX_NBK];
    for (int i = threadIdx.x; i < nbk; i += 256) hist[i] = 0;
    __syncthreads();
    const int lo = blockIdx.x * chunk;
    const int hi = min(lo + chunk, E);
    for (int e = lo + threadIdx.x; e < hi; e += 256)
        atomicAdd(&hist[dst[e] >> 7], 1);
    __syncthreads();
    const int B = gridDim.x;
    for (int i = threadIdx.x; i < nbk; i += 256)
        blkoff[i * B + blockIdx.x] = atomicAdd(&btot[i], hist[i]);
}

// exclusive scan of nbk (<=1024) bucket totals -> obk[nbk+1]  (wave-parallel)
__global__ __launch_bounds__(256) void scan_small_k(const int* __restrict__ btot,
                                                    int* __restrict__ obk, int nbk) {
    __shared__ int sh[MAX_NBK];
    const int tid = threadIdx.x;
    for (int i = tid; i < nbk; i += 256) sh[i] = btot[i];
    __syncthreads();
    if (tid < 64) {
        int run = 0;
        for (int b0 = 0; b0 < nbk; b0 += 64) {
            const int i = b0 + tid;
            int v = (i < nbk) ? sh[i] : 0;
            int inc = v;
#pragma unroll
            for (int o = 1; o < 64; o <<= 1) {
                int u = __shfl_up(inc, o);
                if (tid >= o) inc += u;
            }
            if (i < nbk) sh[i] = run + inc - v;       // exclusive
            run += __shfl(inc, 63);
        }
        if (tid == 0) obk[nbk] = run;                 // total edge count
    }
    __syncthreads();
    for (int i = tid; i < nbk; i += 256) obk[i] = sh[i];
}

__global__ __launch_bounds__(256) void bin_scatter_k(const int* __restrict__ ei, int E,
                                                     const int* __restrict__ obk,
                                                     const int* __restrict__ blkoff,
                                                     int* __restrict__ eb, int nbk,
                                                     int chunk) {
    __shared__ int cur[MAX_NBK];
    __shared__ int off_s[MAX_NBK];
    const int B = gridDim.x;
    for (int i = threadIdx.x; i < nbk; i += 256) {
        cur[i] = 0;
        off_s[i] = obk[i] + blkoff[i * B + blockIdx.x];
    }
    __syncthreads();
    const int lo = blockIdx.x * chunk;
    const int hi = min(lo + chunk, E);
    for (int e = lo + threadIdx.x; e < hi; e += 256) {
        int s = ei[e];
        int d = ei[E + e];
        int b = d >> 7;
        int idx = atomicAdd(&cur[b], 1);
        eb[off_s[b] + idx] = (s << 7) | (d & 127);
    }
}

// bucket CSR build + fused 32-node-group degree sort (perm for the agg kernels)
__global__ __launch_bounds__(256) void bucket_build_k(const int* __restrict__ eb,
                                                      const int* __restrict__ obk,
                                                      int* __restrict__ row_ptr,
                                                      int* __restrict__ col,
                                                      int* __restrict__ perm,
                                                      int n, int nbk) {
    __shared__ int c[128];
    __shared__ int rp[128];
    const int b = blockIdx.x;
    const int t = threadIdx.x;
    const int beg = obk[b];
    const int end = obk[b + 1];
    const int bbase = beg + b * 128;     // preceding buckets are full (128 loops each)
    if (t < 128) c[t] = 1;               // self-loop pre-count
    __syncthreads();
    for (int i = beg + t; i < end; i += 256)
        atomicAdd(&c[eb[i] & 127], 1);
    __syncthreads();
    if (t < 64) {                        // exclusive scan of 128 degrees (wave 0)
        int v0 = c[2 * t], v1 = c[2 * t + 1];
        int pair = v0 + v1;
        int inc = pair;
        for (int o = 1; o < 64; o <<= 1) {
            int u = __shfl_up(inc, o);
            if (t >= o) inc += u;
        }
        int ex = inc - pair;
        rp[2 * t] = bbase + ex;
        rp[2 * t + 1] = bbase + ex + v0;
    }
    __syncthreads();
    const int node = b * 128 + t;
    if (t < 128 && node < n) {
        row_ptr[node] = rp[t];
        col[rp[t]] = node;               // self-loop in slot 0
    }
    if (b == 0 && t == 0) row_ptr[n] = obk[nbk] + n;
    __syncthreads();
    if (t < 128) c[t] = 1;
    __syncthreads();
    for (int i = beg + t; i < end; i += 256) {
        int p = eb[i];
        int dl = p & 127;
        int idx = atomicAdd(&c[dl], 1);
        col[rp[dl] + idx] = p >> 7;
    }
    __syncthreads();
    // c[t] is now the full degree (1 + in-edges). Bitonic-sort each 32-node
    // group by degree; perm[slot] = node. Bijective within 32-node groups so
    // MT=32 agg blocks can use slot = pnode - base for the A-tile row.
    if (t < 128) {
        const int lane5 = t & 31;
        int key = (c[t] << 5) | lane5;   // composite key, distinct
        for (int k = 2; k <= 32; k <<= 1) {
            for (int j = k >> 1; j > 0; j >>= 1) {
                const int pkey = __shfl_xor(key, j);
                const bool up = ((lane5 & k) == 0);
                const bool keep_min = (((lane5 & j) == 0) == up);
                key = keep_min ? min(key, pkey) : max(key, pkey);
            }
        }
        perm[b * 128 + t] = b * 128 + (t & 96) + (key & 31);
    }
}

// ---------------- layer 1 dense: fp32 x -> MFMA bf16 GEMM + attention dots ----

template <int K, int F>
__launch_bounds__(256)
__global__ void gemm_mfma_k(const float* __restrict__ x, const float* __restrict__ W,
                            const float* __restrict__ a_s, const float* __restrict__ a_d,
                            unsigned short* __restrict__ hb, float2* __restrict__ ssd,
                            int n) {
    constexpr int MT = 64;               // rows per block
    constexpr int KP = K + 8;            // padded inner stride (bf16 elems)
    constexpr int NT = F / 16;           // n-tiles per wave
    constexpr int KC = K / 32;           // k-steps

    __shared__ unsigned short xb[MT * KP];
    __shared__ unsigned short wb[F * KP];

    const int tid = threadIdx.x;
    const int lane = tid & 63;
    const int wv = tid >> 6;             // wave id 0..3
    const int base = blockIdx.x * MT;

    for (int i = tid; i < MT * K / 4; i += 256) {
        int row = i / (K / 4);
        int c4 = i % (K / 4);
        float4 v = make_float4(0.f, 0.f, 0.f, 0.f);
        if (base + row < n)
            v = *(const float4*)&x[(size_t)(base + row) * K + 4 * c4];
        ushort4 b;
        b.x = f2bf(v.x); b.y = f2bf(v.y); b.z = f2bf(v.z); b.w = f2bf(v.w);
        *(ushort4*)&xb[row * KP + 4 * c4] = b;
    }
    // W staging, k-contiguous ushort4 stores (lane stride 2*KP B -> ~8 banks)
    for (int i = tid; i < K * F / 4; i += 256) {
        int nn = i % F;
        int k4 = i / F;
        ushort4 b;
        b.x = f2bf(W[(size_t)(4 * k4 + 0) * F + nn]);
        b.y = f2bf(W[(size_t)(4 * k4 + 1) * F + nn]);
        b.z = f2bf(W[(size_t)(4 * k4 + 2) * F + nn]);
        b.w = f2bf(W[(size_t)(4 * k4 + 3) * F + nn]);
        *(ushort4*)&wb[nn * KP + 4 * k4] = b;
    }
    __syncthreads();

    const int mrow = lane & 15;
    const int quad = lane >> 4;

    f32x4 acc[NT];
#pragma unroll
    for (int t = 0; t < NT; ++t) acc[t] = (f32x4){0.f, 0.f, 0.f, 0.f};

#pragma unroll
    for (int kc = 0; kc < KC; ++kc) {
        const int kof = kc * 32 + quad * 8;
        bf16x8 af = *(const bf16x8*)&xb[(wv * 16 + mrow) * KP + kof];
#pragma unroll
        for (int t = 0; t < NT; ++t) {
            bf16x8 bfr = *(const bf16x8*)&wb[(t * 16 + mrow) * KP + kof];
            acc[t] = __builtin_amdgcn_mfma_f32_16x16x32_bf16(af, bfr, acc[t], 0, 0, 0);
        }
    }

    float as_c[NT], ad_c[NT];
#pragma unroll
    for (int t = 0; t < NT; ++t) { as_c[t] = a_s[t * 16 + mrow]; ad_c[t] = a_d[t * 16 + mrow]; }

#pragma unroll
    for (int r = 0; r < 4; ++r) {
        const int node = base + wv * 16 + quad * 4 + r;
        float ps = 0.f, pd = 0.f;
#pragma unroll
        for (int t = 0; t < NT; ++t) {
            ps = fmaf(acc[t][r], as_c[t], ps);
            pd = fmaf(acc[t][r], ad_c[t], pd);
        }
#pragma unroll
        for (int o = 1; o < 16; o <<= 1) {
            ps += __shfl_xor(ps, o);
            pd += __shfl_xor(pd, o);
        }
        if (node < n) {
#pragma unroll
            for (int t = 0; t < NT; ++t)
                hb[(size_t)node * F + t * 16 + mrow] = f2bf(acc[t][r]);
            if (mrow == 0) ssd[node] = make_float2(ps, pd);
        }
    }
}

// ---------------- fused agg(layer i) + gemm(layer i+1) -----------------------
// 128 threads = 2 waves, MT=32 nodes/block. S=4 lanes/node (16 channels/lane).
// Doubled block supply vs MT=64: grid ~3126 (12.2 blocks/CU), LDS 13.8KB ->
// ~11 blocks/CU ceiling; targets the latency-bound gather loop with 2x the
// resident waves. Hot loop branchless + phase-split as before.

template <int K, int F>
__launch_bounds__(128)
__global__ void agg_gemm_k(const int* __restrict__ row_ptr, const int* __restrict__ col,
                           const int* __restrict__ perm,
                           const unsigned short* __restrict__ hbi,
                           const float2* __restrict__ ssdi,
                           const float* __restrict__ bias,
                           const float* __restrict__ W,
                           const float* __restrict__ a_s, const float* __restrict__ a_d,
                           unsigned short* __restrict__ hbo, float2* __restrict__ ssdo,
                           int n) {
    static_assert(K == 64, "agg phase assumes 64 input channels");
    constexpr int S = 4;                 // lanes per node (16 channels each)
    constexpr int MT = 32;               // nodes (= GEMM rows) per block
    constexpr int KP = K + 8;
    constexpr int NT = F / 16;
    constexpr int KC = K / 32;

    __shared__ unsigned short xb[MT * KP];
    __shared__ unsigned short wb[F * KP];

    const int tid = threadIdx.x;
    const int lane = tid & 63;
    const int wv = tid >> 6;             // 0..1
    const int base = blockIdx.x * MT;

    // stage W (read before phase 1; consumed after the single barrier)
    for (int i = tid; i < K * F / 4; i += 128) {
        int nn = i % F;
        int k4 = i / F;
        ushort4 b;
        b.x = f2bf(W[(size_t)(4 * k4 + 0) * F + nn]);
        b.y = f2bf(W[(size_t)(4 * k4 + 1) * F + nn]);
        b.z = f2bf(W[(size_t)(4 * k4 + 2) * F + nn]);
        b.w = f2bf(W[(size_t)(4 * k4 + 3) * F + nn]);
        *(ushort4*)&wb[nn * KP + 4 * k4] = b;
    }

    // ---- phase 1: softmax aggregation, 4 lanes per node (degree-sorted) ----
    const int ls = lane & (S - 1);       // lane in subgroup (channel 16*ls..)
    const int lbase = lane - ls;
    const int nl = tid >> 2;             // sorted slot 0..31
    const int pnode = perm[base + nl];   // node this subgroup aggregates
    const int slot = pnode - base;       // its row in the A-tile (bijective in 32)

    float val[16];
#pragma unroll
    for (int i = 0; i < 16; ++i) val[i] = 0.f;

    if (pnode < n) {
        const int beg = row_ptr[pnode];
        const int end = row_ptr[pnode + 1];
        const float2 sn = ssdi[pnode];
        const float sdv = sn.y;
        float z0 = sn.x + sdv;
        z0 = (z0 > 0.f) ? z0 : NEG_SLOPE * z0;   // self-loop logit = softmax shift

        float s = 0.f;
        f32x2 acc2[8];
#pragma unroll
        for (int i = 0; i < 8; ++i) acc2[i] = (f32x2){0.f, 0.f};

        // prologue: pass-0 logit
        const int j0 = beg + ls;
        const bool vld0 = j0 < end;
        int c_cur = vld0 ? col[j0] : 0;
        float w_cur = 0.f;
        if (vld0) {
            float z = ssdi[c_cur].x + sdv;
            z = (z > 0.f) ? z : NEG_SLOPE * z;
            w_cur = __expf(z - z0);
        }

        for (int b0 = beg; b0 < end; b0 += S) {
            const int jn = b0 + S + ls;
            const bool vn = jn < end;
            const int c_next = vn ? col[jn] : 0;     // issued before gathers

            s += w_cur;
            const unsigned int pk =
                ((unsigned int)f2bf(w_cur) << 17) | (unsigned int)c_cur;

            // phase A: cross-lane moves (pk of the 4 edges of this node)
            unsigned int pe[4];
#pragma unroll
            for (int t = 0; t < 4; ++t)
                pe[t] = (unsigned int)__shfl((int)pk, lbase + t);

            // phase B: 8 gathers (2 per edge) issued back-to-back
            uint4 hv[8];
#pragma unroll
            for (int t = 0; t < 4; ++t) {
                const size_t off = (size_t)(pe[t] & 0x1ffffu) * K + 16 * ls;
                hv[2 * t]     = *(const uint4*)&hbi[off];
                hv[2 * t + 1] = *(const uint4*)&hbi[off + 8];
            }

            __builtin_amdgcn_sched_barrier(0);   // keep consume out of the load pack

            // next-pass logit chain overlaps the in-flight gathers
            float w_next = 0.f;
            if (vn) {
                float z = ssdi[c_next].x + sdv;
                z = (z > 0.f) ? z : NEG_SLOPE * z;
                w_next = __expf(z - z0);
            }

            // phase C: consume (wt == 0 for tail slots -> zero contribution)
#pragma unroll
            for (int t = 0; t < 4; ++t) {
                const float wt = __uint_as_float((pe[t] >> 17) << 16);
                f32x2 p;
                p.x = bf_lo(hv[2 * t].x); p.y = bf_hi(hv[2 * t].x); acc2[0] += p * wt;
                p.x = bf_lo(hv[2 * t].y); p.y = bf_hi(hv[2 * t].y); acc2[1] += p * wt;
                p.x = bf_lo(hv[2 * t].z); p.y = bf_hi(hv[2 * t].z); acc2[2] += p * wt;
                p.x = bf_lo(hv[2 * t].w); p.y = bf_hi(hv[2 * t].w); acc2[3] += p * wt;
                p.x = bf_lo(hv[2 * t + 1].x); p.y = bf_hi(hv[2 * t + 1].x); acc2[4] += p * wt;
                p.x = bf_lo(hv[2 * t + 1].y); p.y = bf_hi(hv[2 * t + 1].y); acc2[5] += p * wt;
                p.x = bf_lo(hv[2 * t + 1].z); p.y = bf_hi(hv[2 * t + 1].z); acc2[6] += p * wt;
                p.x = bf_lo(hv[2 * t + 1].w); p.y = bf_hi(hv[2 * t + 1].w); acc2[7] += p * wt;
            }
            c_cur = c_next;
            w_cur = w_next;
        }
        // reduce s over the 4-lane subgroup
        s += __shfl_xor(s, 1);
        s += __shfl_xor(s, 2);
        const float inv = 1.f / (s + 1e-16f);
#pragma unroll
        for (int i = 0; i < 8; ++i) {
            val[2 * i]     = acc2[i].x;
            val[2 * i + 1] = acc2[i].y;
        }
#pragma unroll
        for (int i = 0; i < 16; ++i)
            val[i] = fmaxf(val[i] * inv + bias[16 * ls + i], 0.f);   // bias + relu
    }
    {   // bf16 row (16 channels/lane) into this node's A-tile slot
        ushort4 p0, p1, p2, p3;
        p0.x = f2bf(val[0]);  p0.y = f2bf(val[1]);  p0.z = f2bf(val[2]);  p0.w = f2bf(val[3]);
        p1.x = f2bf(val[4]);  p1.y = f2bf(val[5]);  p1.z = f2bf(val[6]);  p1.w = f2bf(val[7]);
        p2.x = f2bf(val[8]);  p2.y = f2bf(val[9]);  p2.z = f2bf(val[10]); p2.w = f2bf(val[11]);
        p3.x = f2bf(val[12]); p3.y = f2bf(val[13]); p3.z = f2bf(val[14]); p3.w = f2bf(val[15]);
        *(ushort4*)&xb[slot * KP + 16 * ls]      = p0;
        *(ushort4*)&xb[slot * KP + 16 * ls + 4]  = p1;
        *(ushort4*)&xb[slot * KP + 16 * ls + 8]  = p2;
        *(ushort4*)&xb[slot * KP + 16 * ls + 12] = p3;
    }

    __syncthreads();

    // ---- phase 2: h = o @ W + fused attention dots (both waves) ----
    {
        const int mrow = lane & 15;
        const int quad = lane >> 4;

        f32x4 acc[NT];
#pragma unroll
        for (int t = 0; t < NT; ++t) acc[t] = (f32x4){0.f, 0.f, 0.f, 0.f};

#pragma unroll
        for (int kc = 0; kc < KC; ++kc) {
            const int kof = kc * 32 + quad * 8;
            bf16x8 af = *(const bf16x8*)&xb[(wv * 16 + mrow) * KP + kof];
#pragma unroll
            for (int t = 0; t < NT; ++t) {
                bf16x8 bfr = *(const bf16x8*)&wb[(t * 16 + mrow) * KP + kof];
                acc[t] = __builtin_amdgcn_mfma_f32_16x16x32_bf16(af, bfr, acc[t], 0, 0, 0);
            }
        }

        float as_c[NT], ad_c[NT];
#pragma unroll
        for (int t = 0; t < NT; ++t) { as_c[t] = a_s[t * 16 + mrow]; ad_c[t] = a_d[t * 16 + mrow]; }

#pragma unroll
        for (int r = 0; r < 4; ++r) {
            const int node2 = base + wv * 16 + quad * 4 + r;
            float ps = 0.f, pd = 0.f;
#pragma unroll
            for (int t = 0; t < NT; ++t) {
                ps = fmaf(acc[t][r], as_c[t], ps);
                pd = fmaf(acc[t][r], ad_c[t], pd);
            }
#pragma unroll
            for (int o = 1; o < 16; o <<= 1) {
                ps += __shfl_xor(ps, o);
                pd += __shfl_xor(pd, o);
            }
            if (node2 < n) {
#pragma unroll
                for (int t = 0; t < NT; ++t)
                    hbo[(size_t)node2 * F + t * 16 + mrow] = f2bf(acc[t][r]);
                if (mrow == 0) ssdo[node2] = make_float2(ps, pd);
            }
        }
    }
}

// ---------------- final sparse layer: softmax aggregation + log_softmax ------
// S=16 lanes/node: 4 edge slots (Q=4) x 4 channel octets (NL=4). Branchless
// depth-4 phase-split gathers + degree-sorted node assignment.

template <int F, int S>
__launch_bounds__(256)
__global__ void gat_agg_k(const int* __restrict__ row_ptr, const int* __restrict__ col,
                          const int* __restrict__ perm,
                          const unsigned short* __restrict__ hb,
                          const float2* __restrict__ ssd,
                          const float* __restrict__ bias,
                          float* __restrict__ out, int n) {
    constexpr int NPW = 64 / S;          // nodes per wave
    constexpr int NL = F / 8;            // lanes per row (8 bf16 channels each)
    constexpr int Q = S / NL;            // edge slots
    constexpr int D = S / Q;             // gather depth per pass
    const int lane = threadIdx.x & 63;
    const int ls   = lane % S;           // lane in subgroup
    const int q    = ls / NL;            // edge slot
    const int cl   = ls % NL;            // channel octet index
    const int lbase = lane - ls;         // first lane of subgroup
    const int wave = (blockIdx.x * blockDim.x + threadIdx.x) >> 6;
    const int node = perm[wave * NPW + lane / S];   // degree-sorted slot -> node
    if (node >= n) return;

    const int beg = row_ptr[node];
    const int end = row_ptr[node + 1];
    const float2 sn = ssd[node];
    const float sdv = sn.y;
    float z0 = sn.x + sdv;
    z0 = (z0 > 0.f) ? z0 : NEG_SLOPE * z0;     // self-loop logit = softmax shift

    float s = 0.f;
    f32x2 acc2[4];
#pragma unroll
    for (int i = 0; i < 4; ++i) acc2[i] = (f32x2){0.f, 0.f};

    // prologue: pass-0 logit (one edge per lane)
    const int j0 = beg + ls;
    const bool vld0 = j0 < end;
    int c_cur = vld0 ? col[j0] : 0;
    float w_cur = 0.f;
    if (vld0) {
        float z = ssd[c_cur].x + sdv;
        z = (z > 0.f) ? z : NEG_SLOPE * z;
        w_cur = __expf(z - z0);
    }

    for (int b0 = beg; b0 < end; b0 += S) {
        const int jn = b0 + S + ls;
        const bool vn = jn < end;
        const int c_next = vn ? col[jn] : 0;

        s += w_cur;
        const unsigned int pk =
            ((unsigned int)f2bf(w_cur) << 17) | (unsigned int)c_cur;

        unsigned int pe[D];
#pragma unroll
        for (int t = 0; t < D; ++t)
            pe[t] = (unsigned int)__shfl((int)pk, lbase + Q * t + q);

        uint4 hv[D];
#pragma unroll
        for (int t = 0; t < D; ++t)
            hv[t] = *(const uint4*)&hb[(size_t)(pe[t] & 0x1ffffu) * F + 8 * cl];

        __builtin_amdgcn_sched_barrier(0);

        float w_next = 0.f;
        if (vn) {
            float z = ssd[c_next].x + sdv;
            z = (z > 0.f) ? z : NEG_SLOPE * z;
            w_next = __expf(z - z0);
        }

#pragma unroll
        for (int t = 0; t < D; ++t) {
            const float wt = __uint_as_float((pe[t] >> 17) << 16);
            f32x2 p;
            p.x = bf_lo(hv[t].x); p.y = bf_hi(hv[t].x); acc2[0] += p * wt;
            p.x = bf_lo(hv[t].y); p.y = bf_hi(hv[t].y); acc2[1] += p * wt;
            p.x = bf_lo(hv[t].z); p.y = bf_hi(hv[t].z); acc2[2] += p * wt;
            p.x = bf_lo(hv[t].w); p.y = bf_hi(hv[t].w); acc2[3] += p * wt;
        }
        c_cur = c_next;
        w_cur = w_next;
    }

#pragma unroll
    for (int o = S / 2; o; o >>= 1) s += __shfl_xor(s, o);
    float val[8] = {acc2[0].x, acc2[0].y, acc2[1].x, acc2[1].y,
                    acc2[2].x, acc2[2].y, acc2[3].x, acc2[3].y};
#pragma unroll
    for (int o = NL; o < S; o <<= 1) {
#pragma unroll
        for (int i = 0; i < 8; ++i) val[i] += __shfl_xor(val[i], o);
    }

    const float inv = 1.f / (s + 1e-16f);
#pragma unroll
    for (int i = 0; i < 8; ++i)
        val[i] = val[i] * inv + bias[8 * cl + i];

    // log_softmax over F channels
    float lm = val[0];
#pragma unroll
    for (int i = 1; i < 8; ++i) lm = fmaxf(lm, val[i]);
#pragma unroll
    for (int o = 1; o < NL; o <<= 1) lm = fmaxf(lm, __shfl_xor(lm, o));
    float ex = 0.f;
#pragma unroll
    for (int i = 0; i < 8; ++i) ex += __expf(val[i] - lm);
#pragma unroll
    for (int o = 1; o < NL; o <<= 1) ex += __shfl_xor(ex, o);
    const float lse = lm + __logf(ex);
#pragma unroll
    for (int i = 0; i < 8; ++i) val[i] -= lse;

    if (q == 0) {
        float4 v0 = make_float4(val[0], val[1], val[2], val[3]);
        float4 v1 = make_float4(val[4], val[5], val[6], val[7]);
        *(float4*)&out[(size_t)node * F + 8 * cl] = v0;
        *(float4*)&out[(size_t)node * F + 8 * cl + 4] = v1;
    }
}

// ---------------- launch ----------------

extern "C" void kernel_launch(void* const* d_in, const int* in_sizes, int n_in,
                              void* d_out, int out_size, void* d_ws, size_t ws_size,
                              hipStream_t stream) {
    const float* x  = (const float*)d_in[0];
    const int*   ei = (const int*)d_in[1];
    const float* W1 = (const float*)d_in[2];
    const float* a1s = (const float*)d_in[3];
    const float* a1d = (const float*)d_in[4];
    const float* b1  = (const float*)d_in[5];
    const float* W2 = (const float*)d_in[6];
    const float* a2s = (const float*)d_in[7];
    const float* a2d = (const float*)d_in[8];
    const float* b2  = (const float*)d_in[9];
    const float* W3 = (const float*)d_in[10];
    const float* a3s = (const float*)d_in[11];
    const float* a3d = (const float*)d_in[12];
    const float* b3  = (const float*)d_in[13];

    const int N = in_sizes[0] / 128;
    const int E = in_sizes[1] / 2;
    const int NBK = (N + 127) / 128;
    const int B = BIN_BLOCKS;
    const int GB = (N + 63) / 64;        // 64-row tiles (layer-1 GEMM)
    const int GA = (N + 31) / 32;        // 32-row tiles (fused agg+gemm)

    char* wp = (char*)d_ws;
    auto alloc = [&](size_t bytes) -> void* {
        void* p = wp;
        wp += (bytes + 255) & ~(size_t)255;
        return p;
    };
    int* row_ptr = (int*)alloc((size_t)(N + 1) * 4);
    int* col     = (int*)alloc((size_t)(E + N) * 4);
    int* perm    = (int*)alloc((size_t)NBK * 128 * 4);
    unsigned short* hb1 = (unsigned short*)alloc((size_t)N * 64 * 2);
    unsigned short* hb2 = (unsigned short*)alloc((size_t)N * 64 * 2);
    unsigned short* hb3 = (unsigned short*)alloc((size_t)N * 32 * 2);
    float2* ssd1 = (float2*)alloc((size_t)N * 8);
    float2* ssd2 = (float2*)alloc((size_t)N * 8);
    float2* ssd3 = (float2*)alloc((size_t)N * 8);
    int* btot   = (int*)alloc((size_t)NBK * 4);
    int* blkoff = (int*)alloc((size_t)NBK * B * 4);
    int* obk    = (int*)alloc((size_t)(NBK + 1) * 4);
    int* eb     = (int*)alloc((size_t)E * 4);

    const int chunk = (E + B - 1) / B;

    zero_k<<<(NBK + 255) / 256, 256, 0, stream>>>(btot, NBK);
    bin_hist_k<<<B, 256, 0, stream>>>(ei + E, E, btot, blkoff, NBK, chunk);
    scan_small_k<<<1, 256, 0, stream>>>(btot, obk, NBK);
    bin_scatter_k<<<B, 256, 0, stream>>>(ei, E, obk, blkoff, eb, NBK, chunk);
    bucket_build_k<<<NBK, 256, 0, stream>>>(eb, obk, row_ptr, col, perm, N, NBK);

    // layer 1 GEMM: 128 -> 64 (fp32 x input)
    gemm_mfma_k<128, 64><<<GB, 256, 0, stream>>>(x, W1, a1s, a1d, hb1, ssd1, N);
    // fused: agg layer1 (relu) + GEMM layer2 64 -> 64
    agg_gemm_k<64, 64><<<GA, 128, 0, stream>>>(row_ptr, col, perm, hb1, ssd1, b1,
                                               W2, a2s, a2d, hb2, ssd2, N);
    // fused: agg layer2 (relu) + GEMM layer3 64 -> 32
    agg_gemm_k<64, 32><<<GA, 128, 0, stream>>>(row_ptr, col, perm, hb2, ssd2, b2,
                                               W3, a3s, a3d, hb3, ssd3, N);
    // final agg + log_softmax (fp32 out)
    gat_agg_k<32, 16><<<(N + 15) / 16, 256, 0, stream>>>(
        row_ptr, col, perm, hb3, ssd3, b3, (float*)d_out, N);
}

// Round 9
// 278.153 us; speedup vs baseline: 1.0390x; 1.0379x over previous
//
#include <hip/hip_runtime.h>
#include <cstddef>
#include <cstdint>

#define NEG_SLOPE 0.2f

__device__ __forceinline__ unsigned short f2bf(float f) {
    unsigned int u = __float_as_uint(f);
    u = (u + 0x7fff + ((u >> 16) & 1)) >> 16;   // round-to-nearest-even
    return (unsigned short)u;
}
__device__ __forceinline__ float bf_lo(unsigned int u) { return __uint_as_float(u << 16); }
__device__ __forceinline__ float bf_hi(unsigned int u) { return __uint_as_float(u & 0xffff0000u); }

typedef __attribute__((ext_vector_type(8))) short bf16x8;   // MFMA A/B frag (4 VGPRs)
typedef __attribute__((ext_vector_type(4))) float f32x4;    // MFMA C/D frag
typedef __attribute__((ext_vector_type(2))) float f32x2;    // v_pk_fma_f32 pair

// ---------------- binned CSR build ----------------
// Bucket = dst >> 7 (128 nodes/bucket). Edges packed (src<<7)|dstLow (src<2^17).

constexpr int BIN_BLOCKS = 256;
constexpr int MAX_NBK = 1024;            // supports N <= 131072 (= packing limit)

__global__ __launch_bounds__(256) void zero_k(int* __restrict__ p, int n) {
    int i = blockIdx.x * blockDim.x + threadIdx.x;
    if (i < n) p[i] = 0;
}

__global__ __launch_bounds__(256) void bin_hist_k(const int* __restrict__ dst, int E,
                                                  int* __restrict__ btot,
                                                  int* __restrict__ blkoff,
                                                  int nbk, int chunk) {
    __shared__ int hist[MAX_NBK];
    for (int i = threadIdx.x; i < nbk; i += 256) hist[i] = 0;
    __syncthreads();
    const int lo = blockIdx.x * chunk;
    const int hi = min(lo + chunk, E);
    for (int e = lo + threadIdx.x; e < hi; e += 256)
        atomicAdd(&hist[dst[e] >> 7], 1);
    __syncthreads();
    const int B = gridDim.x;
    for (int i = threadIdx.x; i < nbk; i += 256)
        blkoff[i * B + blockIdx.x] = atomicAdd(&btot[i], hist[i]);
}

// exclusive scan of nbk (<=1024) bucket totals -> obk[nbk+1]  (wave-parallel)
__global__ __launch_bounds__(256) void scan_small_k(const int* __restrict__ btot,
                                                    int* __restrict__ obk, int nbk) {
    __shared__ int sh[MAX_NBK];
    const int tid = threadIdx.x;
    for (int i = tid; i < nbk; i += 256) sh[i] = btot[i];
    __syncthreads();
    if (tid < 64) {
        int run = 0;
        for (int b0 = 0; b0 < nbk; b0 += 64) {
            const int i = b0 + tid;
            int v = (i < nbk) ? sh[i] : 0;
            int inc = v;
#pragma unroll
            for (int o = 1; o < 64; o <<= 1) {
                int u = __shfl_up(inc, o);
                if (tid >= o) inc += u;
            }
            if (i < nbk) sh[i] = run + inc - v;       // exclusive
            run += __shfl(inc, 63);
        }
        if (tid == 0) obk[nbk] = run;                 // total edge count
    }
    __syncthreads();
    for (int i = tid; i < nbk; i += 256) obk[i] = sh[i];
}

__global__ __launch_bounds__(256) void bin_scatter_k(const int* __restrict__ ei, int E,
                                                     const int* __restrict__ obk,
                                                     const int* __restrict__ blkoff,
                                                     int* __restrict__ eb, int nbk,
                                                     int chunk) {
    __shared__ int cur[MAX_NBK];
    __shared__ int off_s[MAX_NBK];
    const int B = gridDim.x;
    for (int i = threadIdx.x; i < nbk; i += 256) {
        cur[i] = 0;
        off_s[i] = obk[i] + blkoff[i * B + blockIdx.x];
    }
    __syncthreads();
    const int lo = blockIdx.x * chunk;
    const int hi = min(lo + chunk, E);
    for (int e = lo + threadIdx.x; e < hi; e += 256) {
        int s = ei[e];
        int d = ei[E + e];
        int b = d >> 7;
        int idx = atomicAdd(&cur[b], 1);
        eb[off_s[b] + idx] = (s << 7) | (d & 127);
    }
}

__global__ __launch_bounds__(256) void bucket_build_k(const int* __restrict__ eb,
                                                      const int* __restrict__ obk,
                                                      int* __restrict__ row_ptr,
                                                      int* __restrict__ col,
                                                      int n, int nbk) {
    __shared__ int c[128];
    __shared__ int rp[128];
    const int b = blockIdx.x;
    const int t = threadIdx.x;
    const int beg = obk[b];
    const int end = obk[b + 1];
    const int bbase = beg + b * 128;     // preceding buckets are full (128 loops each)
    if (t < 128) c[t] = 1;               // self-loop pre-count
    __syncthreads();
    for (int i = beg + t; i < end; i += 256)
        atomicAdd(&c[eb[i] & 127], 1);
    __syncthreads();
    if (t < 64) {                        // exclusive scan of 128 degrees (wave 0)
        int v0 = c[2 * t], v1 = c[2 * t + 1];
        int pair = v0 + v1;
        int inc = pair;
        for (int o = 1; o < 64; o <<= 1) {
            int u = __shfl_up(inc, o);
            if (t >= o) inc += u;
        }
        int ex = inc - pair;
        rp[2 * t] = bbase + ex;
        rp[2 * t + 1] = bbase + ex + v0;
    }
    __syncthreads();
    const int node = b * 128 + t;
    if (t < 128 && node < n) {
        row_ptr[node] = rp[t];
        col[rp[t]] = node;               // self-loop in slot 0
    }
    if (b == 0 && t == 0) row_ptr[n] = obk[nbk] + n;
    __syncthreads();
    if (t < 128) c[t] = 1;
    __syncthreads();
    for (int i = beg + t; i < end; i += 256) {
        int p = eb[i];
        int dl = p & 127;
        int idx = atomicAdd(&c[dl], 1);
        col[rp[dl] + idx] = p >> 7;
    }
}

// ---------------- layer 1 dense: fp32 x -> MFMA bf16 GEMM + attention dots ----

template <int K, int F>
__launch_bounds__(256)
__global__ void gemm_mfma_k(const float* __restrict__ x, const float* __restrict__ W,
                            const float* __restrict__ a_s, const float* __restrict__ a_d,
                            unsigned short* __restrict__ hb, float2* __restrict__ ssd,
                            int n) {
    constexpr int MT = 64;               // rows per block
    constexpr int KP = K + 8;            // padded inner stride (bf16 elems)
    constexpr int NT = F / 16;           // n-tiles per wave
    constexpr int KC = K / 32;           // k-steps

    __shared__ unsigned short xb[MT * KP];
    __shared__ unsigned short wb[F * KP];

    const int tid = threadIdx.x;
    const int lane = tid & 63;
    const int wv = tid >> 6;             // wave id 0..3
    const int base = blockIdx.x * MT;

    for (int i = tid; i < MT * K / 4; i += 256) {
        int row = i / (K / 4);
        int c4 = i % (K / 4);
        float4 v = make_float4(0.f, 0.f, 0.f, 0.f);
        if (base + row < n)
            v = *(const float4*)&x[(size_t)(base + row) * K + 4 * c4];
        ushort4 b;
        b.x = f2bf(v.x); b.y = f2bf(v.y); b.z = f2bf(v.z); b.w = f2bf(v.w);
        *(ushort4*)&xb[row * KP + 4 * c4] = b;
    }
    // W staging, k-contiguous ushort4 stores (lane stride 2*KP B -> ~8 banks)
    for (int i = tid; i < K * F / 4; i += 256) {
        int nn = i % F;
        int k4 = i / F;
        ushort4 b;
        b.x = f2bf(W[(size_t)(4 * k4 + 0) * F + nn]);
        b.y = f2bf(W[(size_t)(4 * k4 + 1) * F + nn]);
        b.z = f2bf(W[(size_t)(4 * k4 + 2) * F + nn]);
        b.w = f2bf(W[(size_t)(4 * k4 + 3) * F + nn]);
        *(ushort4*)&wb[nn * KP + 4 * k4] = b;
    }
    __syncthreads();

    const int mrow = lane & 15;
    const int quad = lane >> 4;

    f32x4 acc[NT];
#pragma unroll
    for (int t = 0; t < NT; ++t) acc[t] = (f32x4){0.f, 0.f, 0.f, 0.f};

#pragma unroll
    for (int kc = 0; kc < KC; ++kc) {
        const int kof = kc * 32 + quad * 8;
        bf16x8 af = *(const bf16x8*)&xb[(wv * 16 + mrow) * KP + kof];
#pragma unroll
        for (int t = 0; t < NT; ++t) {
            bf16x8 bfr = *(const bf16x8*)&wb[(t * 16 + mrow) * KP + kof];
            acc[t] = __builtin_amdgcn_mfma_f32_16x16x32_bf16(af, bfr, acc[t], 0, 0, 0);
        }
    }

    float as_c[NT], ad_c[NT];
#pragma unroll
    for (int t = 0; t < NT; ++t) { as_c[t] = a_s[t * 16 + mrow]; ad_c[t] = a_d[t * 16 + mrow]; }

#pragma unroll
    for (int r = 0; r < 4; ++r) {
        const int node = base + wv * 16 + quad * 4 + r;
        float ps = 0.f, pd = 0.f;
#pragma unroll
        for (int t = 0; t < NT; ++t) {
            ps = fmaf(acc[t][r], as_c[t], ps);
            pd = fmaf(acc[t][r], ad_c[t], pd);
        }
#pragma unroll
        for (int o = 1; o < 16; o <<= 1) {
            ps += __shfl_xor(ps, o);
            pd += __shfl_xor(pd, o);
        }
        if (node < n) {
#pragma unroll
            for (int t = 0; t < NT; ++t)
                hb[(size_t)node * F + t * 16 + mrow] = f2bf(acc[t][r]);
            if (mrow == 0) ssd[node] = make_float2(ps, pd);
        }
    }
}

// ---------------- fused agg(layer i) + gemm(layer i+1) -----------------------
// 512 threads: 8 waves x 8 nodes (S=8 lanes/node) aggregate the 64-row tile
// straight into LDS, then waves 0..3 run the MFMA. Hot loop is BRANCHLESS and
// phase-split: 8 shfl -> 8 gathers -> sched_barrier(0) -> w_next chain ->
// consume. Best-measured configuration (R5: 41.6us/dispatch, ~7% above the
// compulsory-fill x random-64B-service-rate floor of ~39us).

template <int K, int F>
__launch_bounds__(512)
__global__ void agg_gemm_k(const int* __restrict__ row_ptr, const int* __restrict__ col,
                           const unsigned short* __restrict__ hbi,
                           const float2* __restrict__ ssdi,
                           const float* __restrict__ bias,
                           const float* __restrict__ W,
                           const float* __restrict__ a_s, const float* __restrict__ a_d,
                           unsigned short* __restrict__ hbo, float2* __restrict__ ssdo,
                           int n) {
    static_assert(K == 64, "agg phase assumes 64 input channels");
    constexpr int S = 8;                 // lanes per node (= K/8)
    constexpr int MT = 64;               // nodes (= GEMM rows) per block
    constexpr int KP = K + 8;
    constexpr int NT = F / 16;
    constexpr int KC = K / 32;

    __shared__ unsigned short xb[MT * KP];
    __shared__ unsigned short wb[F * KP];

    const int tid = threadIdx.x;
    const int lane = tid & 63;
    const int wv = tid >> 6;             // 0..7
    const int base = blockIdx.x * MT;

    // stage W (read before phase 1; consumed after the single barrier)
    for (int i = tid; i < K * F / 4; i += 512) {
        int nn = i % F;
        int k4 = i / F;
        ushort4 b;
        b.x = f2bf(W[(size_t)(4 * k4 + 0) * F + nn]);
        b.y = f2bf(W[(size_t)(4 * k4 + 1) * F + nn]);
        b.z = f2bf(W[(size_t)(4 * k4 + 2) * F + nn]);
        b.w = f2bf(W[(size_t)(4 * k4 + 3) * F + nn]);
        *(ushort4*)&wb[nn * KP + 4 * k4] = b;
    }

    // ---- phase 1: softmax aggregation, 8 lanes per node ----
    const int ls = lane & (S - 1);       // channel octet index (NL == S, Q == 1)
    const int lbase = lane - ls;
    const int nl = tid >> 3;             // node_local 0..63
    const int node = base + nl;

    float val[8] = {0.f, 0.f, 0.f, 0.f, 0.f, 0.f, 0.f, 0.f};
    if (node < n) {
        const int beg = row_ptr[node];
        const int end = row_ptr[node + 1];
        const float2 sn = ssdi[node];
        const float sdv = sn.y;
        float z0 = sn.x + sdv;
        z0 = (z0 > 0.f) ? z0 : NEG_SLOPE * z0;   // self-loop logit = softmax shift

        float s = 0.f;
        f32x2 acc2[4];
#pragma unroll
        for (int i = 0; i < 4; ++i) acc2[i] = (f32x2){0.f, 0.f};

        // prologue: pass-0 logit
        const int j0 = beg + ls;
        const bool vld0 = j0 < end;
        int c_cur = vld0 ? col[j0] : 0;
        float w_cur = 0.f;
        if (vld0) {
            float z = ssdi[c_cur].x + sdv;
            z = (z > 0.f) ? z : NEG_SLOPE * z;
            w_cur = __expf(z - z0);
        }

        for (int b0 = beg; b0 < end; b0 += S) {
            const int jn = b0 + S + ls;
            const bool vn = jn < end;
            const int c_next = vn ? col[jn] : 0;     // issued before gathers

            s += w_cur;
            const unsigned int pk =
                ((unsigned int)f2bf(w_cur) << 17) | (unsigned int)c_cur;

            // phase A: all cross-lane moves (pk of 8 edges of this node)
            unsigned int pe[8];
#pragma unroll
            for (int t = 0; t < 8; ++t)
                pe[t] = (unsigned int)__shfl((int)pk, lbase + t);

            // phase B: all 8 gathers issued back-to-back, none consumed yet
            uint4 hv[8];
#pragma unroll
            for (int t = 0; t < 8; ++t)
                hv[t] = *(const uint4*)&hbi[(size_t)(pe[t] & 0x1ffffu) * K + 8 * ls];

            __builtin_amdgcn_sched_barrier(0);   // keep consume out of the load pack

            // next-pass logit chain overlaps the 8 in-flight gathers
            float w_next = 0.f;
            if (vn) {
                float z = ssdi[c_next].x + sdv;
                z = (z > 0.f) ? z : NEG_SLOPE * z;
                w_next = __expf(z - z0);
            }

            // phase C: consume (wt == 0 for tail slots -> zero contribution)
#pragma unroll
            for (int t = 0; t < 8; ++t) {
                const float wt = __uint_as_float((pe[t] >> 17) << 16);
                f32x2 p;
                p.x = bf_lo(hv[t].x); p.y = bf_hi(hv[t].x); acc2[0] += p * wt;
                p.x = bf_lo(hv[t].y); p.y = bf_hi(hv[t].y); acc2[1] += p * wt;
                p.x = bf_lo(hv[t].z); p.y = bf_hi(hv[t].z); acc2[2] += p * wt;
                p.x = bf_lo(hv[t].w); p.y = bf_hi(hv[t].w); acc2[3] += p * wt;
            }
            c_cur = c_next;
            w_cur = w_next;
        }
#pragma unroll
        for (int o = S / 2; o; o >>= 1) s += __shfl_xor(s, o);
        const float inv = 1.f / (s + 1e-16f);
        val[0] = acc2[0].x; val[1] = acc2[0].y; val[2] = acc2[1].x; val[3] = acc2[1].y;
        val[4] = acc2[2].x; val[5] = acc2[2].y; val[6] = acc2[3].x; val[7] = acc2[3].y;
#pragma unroll
        for (int i = 0; i < 8; ++i)
            val[i] = fmaxf(val[i] * inv + bias[8 * ls + i], 0.f);   // bias + relu
    }
    {   // bf16 rows straight into the GEMM A-tile (zeros for node >= n)
        ushort4 p0, p1;
        p0.x = f2bf(val[0]); p0.y = f2bf(val[1]); p0.z = f2bf(val[2]); p0.w = f2bf(val[3]);
        p1.x = f2bf(val[4]); p1.y = f2bf(val[5]); p1.z = f2bf(val[6]); p1.w = f2bf(val[7]);
        *(ushort4*)&xb[nl * KP + 8 * ls] = p0;
        *(ushort4*)&xb[nl * KP + 8 * ls + 4] = p1;
    }

    __syncthreads();

    // ---- phase 2: h = o @ W + fused attention dots (waves 0..3) ----
    if (wv < 4) {
        const int mrow = lane & 15;
        const int quad = lane >> 4;

        f32x4 acc[NT];
#pragma unroll
        for (int t = 0; t < NT; ++t) acc[t] = (f32x4){0.f, 0.f, 0.f, 0.f};

#pragma unroll
        for (int kc = 0; kc < KC; ++kc) {
            const int kof = kc * 32 + quad * 8;
            bf16x8 af = *(const bf16x8*)&xb[(wv * 16 + mrow) * KP + kof];
#pragma unroll
            for (int t = 0; t < NT; ++t) {
                bf16x8 bfr = *(const bf16x8*)&wb[(t * 16 + mrow) * KP + kof];
                acc[t] = __builtin_amdgcn_mfma_f32_16x16x32_bf16(af, bfr, acc[t], 0, 0, 0);
            }
        }

        float as_c[NT], ad_c[NT];
#pragma unroll
        for (int t = 0; t < NT; ++t) { as_c[t] = a_s[t * 16 + mrow]; ad_c[t] = a_d[t * 16 + mrow]; }

#pragma unroll
        for (int r = 0; r < 4; ++r) {
            const int node2 = base + wv * 16 + quad * 4 + r;
            float ps = 0.f, pd = 0.f;
#pragma unroll
            for (int t = 0; t < NT; ++t) {
                ps = fmaf(acc[t][r], as_c[t], ps);
                pd = fmaf(acc[t][r], ad_c[t], pd);
            }
#pragma unroll
            for (int o = 1; o < 16; o <<= 1) {
                ps += __shfl_xor(ps, o);
                pd += __shfl_xor(pd, o);
            }
            if (node2 < n) {
#pragma unroll
                for (int t = 0; t < NT; ++t)
                    hbo[(size_t)node2 * F + t * 16 + mrow] = f2bf(acc[t][r]);
                if (mrow == 0) ssdo[node2] = make_float2(ps, pd);
            }
        }
    }
}

// ---------------- final sparse layer: softmax aggregation + log_softmax ------
// S=16 lanes/node: 4 edge slots (Q=4) x 4 channel octets (NL=4). Branchless
// depth-4 phase-split gathers + sched_barrier, as in agg_gemm_k.

template <int F, int S>
__launch_bounds__(256)
__global__ void gat_agg_k(const int* __restrict__ row_ptr, const int* __restrict__ col,
                          const unsigned short* __restrict__ hb,
                          const float2* __restrict__ ssd,
                          const float* __restrict__ bias,
                          float* __restrict__ out, int n) {
    constexpr int NPW = 64 / S;          // nodes per wave
    constexpr int NL = F / 8;            // lanes per row (8 bf16 channels each)
    constexpr int Q = S / NL;            // edge slots
    constexpr int D = S / Q;             // gather depth per pass
    const int lane = threadIdx.x & 63;
    const int ls   = lane % S;           // lane in subgroup
    const int q    = ls / NL;            // edge slot
    const int cl   = ls % NL;            // channel octet index
    const int lbase = lane - ls;         // first lane of subgroup
    const int wave = (blockIdx.x * blockDim.x + threadIdx.x) >> 6;
    const int node = wave * NPW + lane / S;
    if (node >= n) return;

    const int beg = row_ptr[node];
    const int end = row_ptr[node + 1];
    const float2 sn = ssd[node];
    const float sdv = sn.y;
    float z0 = sn.x + sdv;
    z0 = (z0 > 0.f) ? z0 : NEG_SLOPE * z0;     // self-loop logit = softmax shift

    float s = 0.f;
    f32x2 acc2[4];
#pragma unroll
    for (int i = 0; i < 4; ++i) acc2[i] = (f32x2){0.f, 0.f};

    // prologue: pass-0 logit (one edge per lane)
    const int j0 = beg + ls;
    const bool vld0 = j0 < end;
    int c_cur = vld0 ? col[j0] : 0;
    float w_cur = 0.f;
    if (vld0) {
        float z = ssd[c_cur].x + sdv;
        z = (z > 0.f) ? z : NEG_SLOPE * z;
        w_cur = __expf(z - z0);
    }

    for (int b0 = beg; b0 < end; b0 += S) {
        const int jn = b0 + S + ls;
        const bool vn = jn < end;
        const int c_next = vn ? col[jn] : 0;

        s += w_cur;
        const unsigned int pk =
            ((unsigned int)f2bf(w_cur) << 17) | (unsigned int)c_cur;

        unsigned int pe[D];
#pragma unroll
        for (int t = 0; t < D; ++t)
            pe[t] = (unsigned int)__shfl((int)pk, lbase + Q * t + q);

        uint4 hv[D];
#pragma unroll
        for (int t = 0; t < D; ++t)
            hv[t] = *(const uint4*)&hb[(size_t)(pe[t] & 0x1ffffu) * F + 8 * cl];

        __builtin_amdgcn_sched_barrier(0);

        float w_next = 0.f;
        if (vn) {
            float z = ssd[c_next].x + sdv;
            z = (z > 0.f) ? z : NEG_SLOPE * z;
            w_next = __expf(z - z0);
        }

#pragma unroll
        for (int t = 0; t < D; ++t) {
            const float wt = __uint_as_float((pe[t] >> 17) << 16);
            f32x2 p;
            p.x = bf_lo(hv[t].x); p.y = bf_hi(hv[t].x); acc2[0] += p * wt;
            p.x = bf_lo(hv[t].y); p.y = bf_hi(hv[t].y); acc2[1] += p * wt;
            p.x = bf_lo(hv[t].z); p.y = bf_hi(hv[t].z); acc2[2] += p * wt;
            p.x = bf_lo(hv[t].w); p.y = bf_hi(hv[t].w); acc2[3] += p * wt;
        }
        c_cur = c_next;
        w_cur = w_next;
    }

#pragma unroll
    for (int o = S / 2; o; o >>= 1) s += __shfl_xor(s, o);
    float val[8] = {acc2[0].x, acc2[0].y, acc2[1].x, acc2[1].y,
                    acc2[2].x, acc2[2].y, acc2[3].x, acc2[3].y};
#pragma unroll
    for (int o = NL; o < S; o <<= 1) {
#pragma unroll
        for (int i = 0; i < 8; ++i) val[i] += __shfl_xor(val[i], o);
    }

    const float inv = 1.f / (s + 1e-16f);
#pragma unroll
    for (int i = 0; i < 8; ++i)
        val[i] = val[i] * inv + bias[8 * cl + i];

    // log_softmax over F channels
    float lm = val[0];
#pragma unroll
    for (int i = 1; i < 8; ++i) lm = fmaxf(lm, val[i]);
#pragma unroll
    for (int o = 1; o < NL; o <<= 1) lm = fmaxf(lm, __shfl_xor(lm, o));
    float ex = 0.f;
#pragma unroll
    for (int i = 0; i < 8; ++i) ex += __expf(val[i] - lm);
#pragma unroll
    for (int o = 1; o < NL; o <<= 1) ex += __shfl_xor(ex, o);
    const float lse = lm + __logf(ex);
#pragma unroll
    for (int i = 0; i < 8; ++i) val[i] -= lse;

    if (q == 0) {
        float4 v0 = make_float4(val[0], val[1], val[2], val[3]);
        float4 v1 = make_float4(val[4], val[5], val[6], val[7]);
        *(float4*)&out[(size_t)node * F + 8 * cl] = v0;
        *(float4*)&out[(size_t)node * F + 8 * cl + 4] = v1;
    }
}

// ---------------- launch ----------------

extern "C" void kernel_launch(void* const* d_in, const int* in_sizes, int n_in,
                              void* d_out, int out_size, void* d_ws, size_t ws_size,
                              hipStream_t stream) {
    const float* x  = (const float*)d_in[0];
    const int*   ei = (const int*)d_in[1];
    const float* W1 = (const float*)d_in[2];
    const float* a1s = (const float*)d_in[3];
    const float* a1d = (const float*)d_in[4];
    const float* b1  = (const float*)d_in[5];
    const float* W2 = (const float*)d_in[6];
    const float* a2s = (const float*)d_in[7];
    const float* a2d = (const float*)d_in[8];
    const float* b2  = (const float*)d_in[9];
    const float* W3 = (const float*)d_in[10];
    const float* a3s = (const float*)d_in[11];
    const float* a3d = (const float*)d_in[12];
    const float* b3  = (const float*)d_in[13];

    const int N = in_sizes[0] / 128;
    const int E = in_sizes[1] / 2;
    const int NBK = (N + 127) / 128;
    const int B = BIN_BLOCKS;

    char* wp = (char*)d_ws;
    auto alloc = [&](size_t bytes) -> void* {
        void* p = wp;
        wp += (bytes + 255) & ~(size_t)255;
        return p;
    };
    int* row_ptr = (int*)alloc((size_t)(N + 1) * 4);
    int* col     = (int*)alloc((size_t)(E + N) * 4);
    unsigned short* hb1 = (unsigned short*)alloc((size_t)N * 64 * 2);
    unsigned short* hb2 = (unsigned short*)alloc((size_t)N * 64 * 2);
    unsigned short* hb3 = (unsigned short*)alloc((size_t)N * 32 * 2);
    float2* ssd1 = (float2*)alloc((size_t)N * 8);
    float2* ssd2 = (float2*)alloc((size_t)N * 8);
    float2* ssd3 = (float2*)alloc((size_t)N * 8);
    int* btot   = (int*)alloc((size_t)NBK * 4);
    int* blkoff = (int*)alloc((size_t)NBK * B * 4);
    int* obk    = (int*)alloc((size_t)(NBK + 1) * 4);
    int* eb     = (int*)alloc((size_t)E * 4);

    const int chunk = (E + B - 1) / B;

    zero_k<<<(NBK + 255) / 256, 256, 0, stream>>>(btot, NBK);
    bin_hist_k<<<B, 256, 0, stream>>>(ei + E, E, btot, blkoff, NBK, chunk);
    scan_small_k<<<1, 256, 0, stream>>>(btot, obk, NBK);
    bin_scatter_k<<<B, 256, 0, stream>>>(ei, E, obk, blkoff, eb, NBK, chunk);
    bucket_build_k<<<NBK, 256, 0, stream>>>(eb, obk, row_ptr, col, N, NBK);

    const int GB = (N + 63) / 64;

    // layer 1 GEMM: 128 -> 64 (fp32 x input)
    gemm_mfma_k<128, 64><<<GB, 256, 0, stream>>>(x, W1, a1s, a1d, hb1, ssd1, N);
    // fused: agg layer1 (relu) + GEMM layer2 64 -> 64
    agg_gemm_k<64, 64><<<GB, 512, 0, stream>>>(row_ptr, col, hb1, ssd1, b1,
                                               W2, a2s, a2d, hb2, ssd2, N);
    // fused: agg layer2 (relu) + GEMM layer3 64 -> 32
    agg_gemm_k<64, 32><<<GB, 512, 0, stream>>>(row_ptr, col, hb2, ssd2, b2,
                                               W3, a3s, a3d, hb3, ssd3, N);
    // final agg + log_softmax (fp32 out)
    gat_agg_k<32, 16><<<(N + 15) / 16, 256, 0, stream>>>(
        row_ptr, col, hb3, ssd3, b3, (float*)d_out, N);
}